// Round 9
// baseline (844.999 us; speedup 1.0000x reference)
//
#include <hip/hip_runtime.h>

typedef __attribute__((ext_vector_type(8))) __bf16 bf16x8;
typedef __attribute__((ext_vector_type(4))) float f32x4;

typedef __attribute__((address_space(1))) void gvoid;
typedef __attribute__((address_space(3))) void lvoid;

__device__ __forceinline__ float bf2f(unsigned int u) {
    union { unsigned int u; float f; } v; v.u = u << 16; return v.f;
}
__device__ __forceinline__ unsigned short f2bf(float f) {
    union { float f; unsigned int u; } v; v.f = f;
    unsigned int r = v.u + 0x7fffu + ((v.u >> 16) & 1u);
    return (unsigned short)(r >> 16);
}
__device__ __forceinline__ unsigned int pack2(float a, float b) {
    return (unsigned int)f2bf(a) | ((unsigned int)f2bf(b) << 16);
}
__device__ __forceinline__ void async16(const void* g, void* l) {
    __builtin_amdgcn_global_load_lds((gvoid*)g, (lvoid*)l, 16, 0, 0);
}
// 2^x via v_exp_f32 (native). __exp2f is NOT declared in this env's headers.
__device__ __forceinline__ float exp2f_hw(float x) {
    return __builtin_amdgcn_exp2f(x);
}

// sum of squares of 8 bf16 (fp32 accumulation)
__device__ __forceinline__ float ssq8(bf16x8 v) {
    const unsigned int* u = (const unsigned int*)&v;
    float s = 0.0f;
#pragma unroll
    for (int j = 0; j < 4; ++j) {
        float x0 = bf2f(u[j] & 0xffffu), x1 = bf2f(u[j] >> 16);
        s += x0 * x0 + x1 * x1;
    }
    return s;
}
// RMSNorm(+scale)+RoPE applied to 8 bf16 (4 rope pairs, cols even-aligned).
// sc -> scale[gc..gc+7]; per -> &pe[(l*64 + gc/2)*4] (4 consecutive float4).
__device__ __forceinline__ bf16x8 normrope8(bf16x8 v, float rr,
                                            const float* __restrict__ sc,
                                            const float* __restrict__ per) {
    const unsigned int* u = (const unsigned int*)&v;
    bf16x8 out;
    unsigned int* ou = (unsigned int*)&out;
#pragma unroll
    for (int j = 0; j < 4; ++j) {
        float x0 = bf2f(u[j] & 0xffffu), x1 = bf2f(u[j] >> 16);
        float y0 = x0 * rr * sc[2 * j], y1 = x1 * rr * sc[2 * j + 1];
        float4 p4 = *(const float4*)(per + 4 * j);
        ou[j] = pack2(p4.x * y0 + p4.y * y1, p4.z * y0 + p4.w * y1);
    }
    return out;
}

// ============================ FAST PATH ====================================

// Fused fp32->bf16 convert of all three tensors in ONE launch (dst regions
// are contiguous in ws: xb @0 | wqkvb @786432 | wprojb @4325376, uint4 units).
__global__ __launch_bounds__(256)
void cvt_all(const float4* __restrict__ x, const float4* __restrict__ wqkv,
             const float4* __restrict__ wproj, uint4* __restrict__ dst) {
    int i = blockIdx.x * 256 + threadIdx.x;
    const float4* s; uint4* d; int off;
    if (i < 786432)       { s = x;     d = dst;           off = i; }
    else if (i < 4325376) { s = wqkv;  d = dst + 786432;  off = i - 786432; }
    else if (i < 5505024) { s = wproj; d = dst + 4325376; off = i - 4325376; }
    else return;
    float4 a = s[2 * off], b = s[2 * off + 1];
    uint4 o;
    o.x = pack2(a.x, a.y); o.y = pack2(a.z, a.w);
    o.z = pack2(b.x, b.y); o.w = pack2(b.z, b.w);
    d[off] = o;
}

// ---- 128x128 ring core — retained for gemm_proj (round-3 proven) ----
#define GEMM_CORE(A_, lda_, B_, ldb_, K_)                                        \
    __shared__ __align__(16) unsigned short As[4][4096];                         \
    __shared__ __align__(16) unsigned short Bs[4][4096];                         \
    const int t = threadIdx.x, lane = t & 63;                                    \
    const int wm = t >> 7, wn = (t >> 6) & 1;                                    \
    const int lr = lane & 15, kc = lane >> 4;                                    \
    const int NK = (K_) / 32;                                                    \
    const int e0 = t * 8, e1 = (256 + t) * 8;                                    \
    const int r0 = e0 >> 5, c0 = (e0 >> 3) & 3;                                  \
    const int r1 = e1 >> 5, c1 = (e1 >> 3) & 3;                                  \
    const int g0 = (c0 ^ ((r0 >> 1) & 3)) * 8;                                   \
    const int g1 = (c1 ^ ((r1 >> 1) & 3)) * 8;                                   \
    const unsigned short* Ag0 = &(A_)[(size_t)(m0 + r0) * (lda_) + g0];          \
    const unsigned short* Ag1 = &(A_)[(size_t)(m0 + r1) * (lda_) + g1];          \
    const unsigned short* Bg0 = &(B_)[(size_t)(n0 + r0) * (ldb_) + g0];          \
    const unsigned short* Bg1 = &(B_)[(size_t)(n0 + r1) * (ldb_) + g1];          \
    f32x4 acc[4][4] = {};                                                        \
    RSTAGE(0) RSTAGE(1) RSTAGE(2)                                                \
    asm volatile("s_waitcnt vmcnt(8)" ::: "memory");                             \
    __builtin_amdgcn_s_barrier();                                                \
    for (int kt = 0; kt < NK; ++kt) {                                            \
        const int sl = kt & 3;                                                   \
        bf16x8 af[4], bfr[4];                                                    \
        _Pragma("unroll")                                                        \
        for (int i = 0; i < 4; ++i) {                                            \
            int ra = wm * 64 + i * 16 + lr;                                      \
            int rb = wn * 64 + i * 16 + lr;                                      \
            af[i]  = *(const bf16x8*)&As[sl][ra * 32 + ((kc ^ ((ra >> 1) & 3)) * 8)]; \
            bfr[i] = *(const bf16x8*)&Bs[sl][rb * 32 + ((kc ^ ((rb >> 1) & 3)) * 8)]; \
        }                                                                        \
        if (kt + 3 < NK) RSTAGE(kt + 3)                                          \
        asm volatile("s_waitcnt lgkmcnt(0)" ::: "memory");                       \
        __builtin_amdgcn_sched_barrier(0);                                       \
        __builtin_amdgcn_s_setprio(1);                                           \
        _Pragma("unroll")                                                        \
        for (int mi = 0; mi < 4; ++mi)                                           \
            _Pragma("unroll")                                                    \
            for (int ni = 0; ni < 4; ++ni)                                       \
                acc[mi][ni] = __builtin_amdgcn_mfma_f32_16x16x32_bf16(           \
                    af[mi], bfr[ni], acc[mi][ni], 0, 0, 0);                      \
        __builtin_amdgcn_s_setprio(0);                                           \
        if (kt + 3 < NK)      { asm volatile("s_waitcnt vmcnt(8)" ::: "memory"); } \
        else if (kt + 2 < NK) { asm volatile("s_waitcnt vmcnt(4)" ::: "memory"); } \
        else if (kt + 1 < NK) { asm volatile("s_waitcnt vmcnt(0)" ::: "memory"); } \
        __builtin_amdgcn_s_barrier();                                            \
    }

#define RSTAGE(kt_) { const int s_ = (kt_) & 3; const size_t k_ = (size_t)(kt_) * 32; \
        async16(Ag0 + k_, &As[s_][e0]); async16(Ag1 + k_, &As[s_][e1]);               \
        async16(Bg0 + k_, &Bs[s_][e0]); async16(Bg1 + k_, &Bs[s_][e1]); }

// Fused QKV GEMM — EXACT round-4 config (fastest measured: ~180 µs).
// 128x256 tile, 4 waves x [128m x 64n], BK=32, 3-slot LDS ring (72 KiB,
// 2 blocks/CU), depth-2 prefetch, counted vmcnt(6). No XCD remap.
// A=xb[2048][3072], B=wqkvb[9216][3072].
// cols <6144 -> qk[row][col]; cols >=6144 -> vt[col-6144][row] (V transposed).
__global__ __launch_bounds__(256, 2)
void gemm_qkv(const unsigned short* __restrict__ A, const unsigned short* __restrict__ B,
              unsigned short* __restrict__ qk, unsigned short* __restrict__ vt) {
    __shared__ __align__(16) unsigned short As[3][4096];   // 128 x 32
    __shared__ __align__(16) unsigned short Bs[3][8192];   // 256 x 32
    const int n0 = blockIdx.x * 256, m0 = blockIdx.y * 128;
    const int t = threadIdx.x, lane = t & 63, w = t >> 6;
    const int lr = lane & 15, kc = lane >> 4;
    const int NK = 96;                        // 3072 / 32

    const int ea0 = t * 8,         ra0 = ea0 >> 5, ca0 = (ea0 >> 3) & 3;
    const int ea1 = (256 + t) * 8, ra1 = ea1 >> 5, ca1 = (ea1 >> 3) & 3;
    const int ga0 = (ca0 ^ ((ra0 >> 1) & 3)) * 8;
    const int ga1 = (ca1 ^ ((ra1 >> 1) & 3)) * 8;
    const unsigned short* Ag0 = &A[(size_t)(m0 + ra0) * 3072 + ga0];
    const unsigned short* Ag1 = &A[(size_t)(m0 + ra1) * 3072 + ga1];
    int eb[4];
    const unsigned short* Bg[4];
#pragma unroll
    for (int i = 0; i < 4; ++i) {
        eb[i] = (i * 256 + t) * 8;
        int rb = eb[i] >> 5, cb = (eb[i] >> 3) & 3;
        int gb = (cb ^ ((rb >> 1) & 3)) * 8;
        Bg[i] = &B[(size_t)(n0 + rb) * 3072 + gb];
    }

#define QSTAGE(kt_) { const int s_ = (kt_) % 3; const size_t k_ = (size_t)(kt_) * 32; \
        async16(Ag0 + k_, &As[s_][ea0]); async16(Ag1 + k_, &As[s_][ea1]);             \
        async16(Bg[0] + k_, &Bs[s_][eb[0]]); async16(Bg[1] + k_, &Bs[s_][eb[1]]);     \
        async16(Bg[2] + k_, &Bs[s_][eb[2]]); async16(Bg[3] + k_, &Bs[s_][eb[3]]); }

    f32x4 acc[8][4] = {};

    QSTAGE(0) QSTAGE(1)
    asm volatile("s_waitcnt vmcnt(6)" ::: "memory");
    __builtin_amdgcn_s_barrier();

    for (int kt = 0; kt < NK; ++kt) {
        const int sl = kt % 3;
        bf16x8 af[8], bfr[4];
#pragma unroll
        for (int i = 0; i < 8; ++i) {
            int ra = i * 16 + lr;
            af[i] = *(const bf16x8*)&As[sl][ra * 32 + ((kc ^ ((ra >> 1) & 3)) * 8)];
        }
#pragma unroll
        for (int i = 0; i < 4; ++i) {
            int rb = w * 64 + i * 16 + lr;
            bfr[i] = *(const bf16x8*)&Bs[sl][rb * 32 + ((kc ^ ((rb >> 1) & 3)) * 8)];
        }
        if (kt + 2 < NK) QSTAGE(kt + 2)
        asm volatile("s_waitcnt lgkmcnt(0)" ::: "memory");
        __builtin_amdgcn_sched_barrier(0);
        __builtin_amdgcn_s_setprio(1);
#pragma unroll
        for (int mi = 0; mi < 8; ++mi)
#pragma unroll
            for (int ni = 0; ni < 4; ++ni)
                acc[mi][ni] = __builtin_amdgcn_mfma_f32_16x16x32_bf16(
                    af[mi], bfr[ni], acc[mi][ni], 0, 0, 0);
        __builtin_amdgcn_s_setprio(0);
        if (kt + 2 < NK) { asm volatile("s_waitcnt vmcnt(6)" ::: "memory"); }
        else             { asm volatile("s_waitcnt vmcnt(0)" ::: "memory"); }
        __builtin_amdgcn_s_barrier();
    }
#undef QSTAGE

    const int rb0 = kc * 4;
#pragma unroll
    for (int mi = 0; mi < 8; ++mi)
#pragma unroll
        for (int ni = 0; ni < 4; ++ni) {
            int col = n0 + w * 64 + ni * 16 + lr;
#pragma unroll
            for (int r = 0; r < 4; ++r) {
                int row = m0 + mi * 16 + rb0 + r;
                unsigned short v = f2bf(acc[mi][ni][r]);
                if (col < 6144) qk[(size_t)row * 6144 + col] = v;
                else            vt[(size_t)(col - 6144) * 2048 + row] = v;
            }
        }
}

// Proj GEMM: A=qk(attn out, lda 6144), B=wprojb[3072][3072], fp32 out + bias.
__global__ __launch_bounds__(256, 2)
void gemm_proj(const unsigned short* __restrict__ A, const unsigned short* __restrict__ B,
               const float* __restrict__ bias, float* __restrict__ out) {
    const int n0 = blockIdx.x * 128, m0 = blockIdx.y * 128;
    GEMM_CORE(A, 6144, B, 3072, 3072)
    const int rb0 = kc * 4;
#pragma unroll
    for (int mi = 0; mi < 4; ++mi)
#pragma unroll
        for (int ni = 0; ni < 4; ++ni) {
            int col = n0 + wn * 64 + ni * 16 + lr;
            float badd = bias[col];
#pragma unroll
            for (int r = 0; r < 4; ++r) {
                int row = m0 + wm * 64 + mi * 16 + rb0 + r;
                out[(size_t)row * 3072 + col] = acc[mi][ni][r] + badd;
            }
        }
}

// Flash attention v5: block = 1 head x 128 q rows (4 waves x 32 rows).
// ROUND-9 CHANGE: norm_rope FUSED (the standalone kernel re-read/re-wrote
// 50 MB of qk purely to transform data attn2 reloads). Q: RMS+RoPE applied
// to aq fragments at block start (row sum = local + shfl_xor(16,32) over the
// 4 kc-groups = exactly 128 elems; rope pairs adjacent in-lane). K: applied
// on the reg-staged prefetch path before ds_write (16-lane row-group sum via
// shfl_xor(1,2,4,8)); tile 0 moved from async16 to the same reg-stage path.
// V untouched. K region of qk is now read-only. fp32 math element-identical
// to norm_rope (only summation order differs).
// Round-8 deferred reductions kept (2 ballots/iter, final sum reduce once).
// Grid (24,16)=384 blocks, 48KB LDS -> 3 blocks/CU. T14 prefetch kept.
__global__ __launch_bounds__(256, 2)
void attn2(unsigned short* __restrict__ qk, const unsigned short* __restrict__ vt,
           const float* __restrict__ pe, const float* __restrict__ q_scale,
           const float* __restrict__ k_scale) {
    __shared__ __align__(16) unsigned short Ks[64 * 128];
    __shared__ __align__(16) unsigned short Vs[128 * 64];
    __shared__ __align__(16) unsigned short Ps[4 * 32 * 64];
    const int t = threadIdx.x, lane = t & 63, w = t >> 6;
    const int h = blockIdx.x, qblk = blockIdx.y * 128;
    const int lr = lane & 15, kc = lane >> 4;
    const float sc2 = 0.08838834764831845f * 1.4426950408889634f; // scale*log2e
    const float THR = 62.7f;                                      // 8 / sc2

    // per-thread K/V staging coords (shared by tile-0 and prefetch paths)
    int krow[4], kgc[4], vrow[4], vgc[4];
#pragma unroll
    for (int i = 0; i < 4; ++i) {
        int idx = i * 256 + t;
        krow[i] = idx >> 4;                       // 0..63 (key within tile)
        kgc[i]  = ((idx & 15) ^ (krow[i] & 15)) * 8;
        vrow[i] = idx >> 3;                       // 0..127 (d)
        vgc[i]  = ((idx & 7) ^ (vrow[i] & 7)) * 8;
    }

    // ---- load Q fragments and apply RMSNorm+RoPE (once per block) ----
    bf16x8 aq[2][4];
#pragma unroll
    for (int mf = 0; mf < 2; ++mf)
#pragma unroll
        for (int ks = 0; ks < 4; ++ks)
            aq[mf][ks] = *(const bf16x8*)&qk[(size_t)(qblk + w * 32 + mf * 16 + lr) * 6144 + h * 128 + ks * 32 + kc * 8];
#pragma unroll
    for (int mf = 0; mf < 2; ++mf) {
        float ss = 0.0f;
#pragma unroll
        for (int ks = 0; ks < 4; ++ks) ss += ssq8(aq[mf][ks]);
        ss += __shfl_xor(ss, 16); ss += __shfl_xor(ss, 32);   // 4 kc-groups = 128 elems
        float rr = rsqrtf(ss * (1.0f / 128.0f) + 1e-6f);
        int lq = qblk + w * 32 + mf * 16 + lr;
#pragma unroll
        for (int ks = 0; ks < 4; ++ks) {
            int c0 = ks * 32 + kc * 8;
            aq[mf][ks] = normrope8(aq[mf][ks], rr, q_scale + c0,
                                   pe + ((size_t)lq * 64 + (c0 >> 1)) * 4);
        }
    }

    f32x4 o[2][8] = {};
    float mst[2][4], lpart[2][4];
#pragma unroll
    for (int mf = 0; mf < 2; ++mf)
#pragma unroll
        for (int r = 0; r < 4; ++r) { mst[mf][r] = -1e30f; lpart[mf][r] = 0.0f; }

    unsigned short* Pw = &Ps[w * 2048];

    // ---- prologue: reg-stage tile kb=0, transform K, write to LDS ----
    {
        bf16x8 pk0[4], pv0[4];
#pragma unroll
        for (int i = 0; i < 4; ++i) {
            pk0[i] = *(const bf16x8*)&qk[(size_t)krow[i] * 6144 + 3072 + h * 128 + kgc[i]];
            pv0[i] = *(const bf16x8*)&vt[(size_t)(h * 128 + vrow[i]) * 2048 + vgc[i]];
        }
#pragma unroll
        for (int i = 0; i < 4; ++i) {
            float ss = ssq8(pk0[i]);
            ss += __shfl_xor(ss, 1); ss += __shfl_xor(ss, 2);
            ss += __shfl_xor(ss, 4); ss += __shfl_xor(ss, 8);   // 16-lane row group
            float rr = rsqrtf(ss * (1.0f / 128.0f) + 1e-6f);
            pk0[i] = normrope8(pk0[i], rr, k_scale + kgc[i],
                               pe + ((size_t)krow[i] * 64 + (kgc[i] >> 1)) * 4);
        }
#pragma unroll
        for (int i = 0; i < 4; ++i) {
            int e = (i * 256 + t) * 8;
            *(bf16x8*)&Ks[e] = pk0[i];
            *(bf16x8*)&Vs[e] = pv0[i];
        }
    }

    for (int kb = 0; kb < 2048; kb += 64) {
        __syncthreads();                 // tile kb present in Ks/Vs

        // T14: issue register prefetch of tile kb+64 (hidden under compute)
        bf16x8 pk[4], pv[4];
        const bool pf = (kb + 64) < 2048;
        if (pf) {
#pragma unroll
            for (int i = 0; i < 4; ++i) {
                pk[i] = *(const bf16x8*)&qk[(size_t)(kb + 64 + krow[i]) * 6144 + 3072 + h * 128 + kgc[i]];
                pv[i] = *(const bf16x8*)&vt[(size_t)(h * 128 + vrow[i]) * 2048 + kb + 64 + vgc[i]];
            }
        }

        // S = Q K^T  (each bk read feeds both mf halves)
        f32x4 s[2][4] = {};
#pragma unroll
        for (int nt = 0; nt < 4; ++nt) {
            int rk = nt * 16 + lr;
#pragma unroll
            for (int ks = 0; ks < 4; ++ks) {
                int ck = ks * 4 + kc;
                bf16x8 bk = *(const bf16x8*)&Ks[rk * 128 + ((ck ^ (rk & 15)) * 8)];
#pragma unroll
                for (int mf = 0; mf < 2; ++mf)
                    s[mf][nt] = __builtin_amdgcn_mfma_f32_16x16x32_bf16(aq[mf][ks], bk, s[mf][nt], 0, 0, 0);
            }
        }

        // softmax, exp2 domain, fully deferred reductions
#pragma unroll
        for (int mf = 0; mf < 2; ++mf) {
            float lm[4]; bool need = false;
#pragma unroll
            for (int r = 0; r < 4; ++r) {
                lm[r] = fmaxf(fmaxf(s[mf][0][r], s[mf][1][r]), fmaxf(s[mf][2][r], s[mf][3][r]));
                need = need || (lm[r] > mst[mf][r] + THR);
            }
            if (__ballot(need) != 0ull) {      // rare; always on first tile
#pragma unroll
                for (int r = 0; r < 4; ++r) {
                    float vmax = lm[r];
#pragma unroll
                    for (int off = 8; off >= 1; off >>= 1) vmax = fmaxf(vmax, __shfl_xor(vmax, off));
                    float mn = fmaxf(mst[mf][r], vmax);
                    float al = exp2f_hw((mst[mf][r] - mn) * sc2);
                    mst[mf][r] = mn;
                    lpart[mf][r] *= al;
#pragma unroll
                    for (int dt = 0; dt < 8; ++dt) o[mf][dt][r] *= al;
                }
            }
#pragma unroll
            for (int r = 0; r < 4; ++r) {
                float ps = 0.0f;
#pragma unroll
                for (int nt = 0; nt < 4; ++nt) {
                    float p = exp2f_hw((s[mf][nt][r] - mst[mf][r]) * sc2);
                    s[mf][nt][r] = p;
                    ps += p;
                }
                lpart[mf][r] += ps;            // per-lane partial; no shuffles
            }
        }

        // P (C-layout) -> per-wave LDS [32 q][64 kk], chunk ^= (q&7)
#pragma unroll
        for (int mf = 0; mf < 2; ++mf)
#pragma unroll
            for (int nt = 0; nt < 4; ++nt) {
                int col = nt * 16 + lr;
                int chunk = col >> 3, cin = col & 7;
#pragma unroll
                for (int r = 0; r < 4; ++r) {
                    int q = mf * 16 + kc * 4 + r;
                    Pw[q * 64 + ((chunk ^ (q & 7)) * 8 + cin)] = f2bf(s[mf][nt][r]);
                }
            }

        // O += P @ V  (each bv read feeds both mf halves)
#pragma unroll
        for (int ks2 = 0; ks2 < 2; ++ks2) {
            int ck = ks2 * 4 + kc;
            bf16x8 ap[2];
#pragma unroll
            for (int mf = 0; mf < 2; ++mf) {
                int q = mf * 16 + lr;
                ap[mf] = *(const bf16x8*)&Pw[q * 64 + ((ck ^ (q & 7)) * 8)];
            }
#pragma unroll
            for (int dt = 0; dt < 8; ++dt) {
                int rv = dt * 16 + lr;
                bf16x8 bv = *(const bf16x8*)&Vs[rv * 64 + ((ck ^ (rv & 7)) * 8)];
#pragma unroll
                for (int mf = 0; mf < 2; ++mf)
                    o[mf][dt] = __builtin_amdgcn_mfma_f32_16x16x32_bf16(ap[mf], bv, o[mf][dt], 0, 0, 0);
            }
        }
        __syncthreads();                 // all reads of tile kb done

        if (pf) {
            // transform K of tile kb+64 (loads have had the whole compute
            // section to land), then write K/V to LDS
#pragma unroll
            for (int i = 0; i < 4; ++i) {
                float ss = ssq8(pk[i]);
                ss += __shfl_xor(ss, 1); ss += __shfl_xor(ss, 2);
                ss += __shfl_xor(ss, 4); ss += __shfl_xor(ss, 8);
                float rr = rsqrtf(ss * (1.0f / 128.0f) + 1e-6f);
                pk[i] = normrope8(pk[i], rr, k_scale + kgc[i],
                                  pe + ((size_t)(kb + 64 + krow[i]) * 64 + (kgc[i] >> 1)) * 4);
            }
#pragma unroll
            for (int i = 0; i < 4; ++i) {
                int e = (i * 256 + t) * 8;
                *(bf16x8*)&Ks[e] = pk[i];
                *(bf16x8*)&Vs[e] = pv[i];
            }
        }
    }

    // final cross-lane reduction of lpart (once), then write
#pragma unroll
    for (int mf = 0; mf < 2; ++mf)
#pragma unroll
        for (int r = 0; r < 4; ++r) {
            float ps = lpart[mf][r];
#pragma unroll
            for (int off = 8; off >= 1; off >>= 1) ps += __shfl_xor(ps, off);
            lpart[mf][r] = ps;
        }
#pragma unroll
    for (int mf = 0; mf < 2; ++mf)
#pragma unroll
        for (int dt = 0; dt < 8; ++dt)
#pragma unroll
            for (int r = 0; r < 4; ++r) {
                int row = qblk + w * 32 + mf * 16 + kc * 4 + r;
                qk[(size_t)row * 6144 + h * 128 + dt * 16 + lr] = f2bf(o[mf][dt][r] / lpart[mf][r]);
            }
}

// ===================== SHARED (slow path only now) =========================

// In-place RMSNorm + RoPE on qk[2048][6144] bf16 (q cols 0..3071, k 3072+).
__global__ __launch_bounds__(256)
void norm_rope(unsigned short* __restrict__ qk, const float* __restrict__ pe,
               const float* __restrict__ q_scale, const float* __restrict__ k_scale) {
    const int wid = threadIdx.x >> 6, lane = threadIdx.x & 63;
    int pid = blockIdx.x * 4 + wid;
    const int isK = pid >= 49152;
    int p2 = isK ? pid - 49152 : pid;
    const int h = p2 >> 11, l = p2 & 2047;

    unsigned short* src = qk + (size_t)l * 6144 + (isK ? 3072 : 0) + h * 128 + lane * 2;
    unsigned int xu = *(const unsigned int*)src;
    float x0 = bf2f(xu & 0xffffu), x1 = bf2f(xu >> 16);
    float ss = x0 * x0 + x1 * x1;
#pragma unroll
    for (int off = 32; off >= 1; off >>= 1) ss += __shfl_xor(ss, off);
    float rr = rsqrtf(ss * (1.0f / 128.0f) + 1e-6f);

    const float* sc = isK ? k_scale : q_scale;
    float2 s2 = *(const float2*)(sc + lane * 2);
    float y0 = x0 * rr * s2.x;
    float y1 = x1 * rr * s2.y;

    float4 p4 = *(const float4*)(pe + ((size_t)l * 64 + lane) * 4);
    float o0 = p4.x * y0 + p4.y * y1;
    float o1 = p4.z * y0 + p4.w * y1;

    *(unsigned int*)src = pack2(o0, o1);
}

// ===================== SLOW PATH (round-4, proven) =========================

template <bool A32, bool B32, bool C32, bool HAS_BIAS, bool TRANS_C>
__global__ __launch_bounds__(256, 2)
void gemm_bt(const void* __restrict__ Ap, const void* __restrict__ Bp,
             const float* __restrict__ bias, void* __restrict__ Cp,
             int M, int N, int K, int lda, int ldc) {
    __shared__ __align__(16) unsigned short As[128 * 40];
    __shared__ __align__(16) unsigned short Bs[128 * 40];
    const int t = threadIdx.x, lane = t & 63;
    const int wm = t >> 7, wn = (t >> 6) & 1;
    const int m0 = blockIdx.x * 128, n0 = blockIdx.y * 128;
    const int lr = lane & 15, kc = lane >> 4;
    f32x4 acc[4][4] = {};

    for (int k0 = 0; k0 < K; k0 += 32) {
        float4 ra32[4], rb32[4];
        bf16x8 ra16[2], rb16[2];
        if constexpr (A32) {
            const float* A = (const float*)Ap;
#pragma unroll
            for (int i = 0; i < 4; ++i) {
                int idx = i * 256 + t, row = idx >> 3, c4 = idx & 7;
                ra32[i] = *(const float4*)&A[(size_t)(m0 + row) * lda + k0 + c4 * 4];
            }
        } else {
            const unsigned short* A = (const unsigned short*)Ap;
#pragma unroll
            for (int i = 0; i < 2; ++i) {
                int idx = i * 256 + t, row = idx >> 2, c8 = idx & 3;
                ra16[i] = *(const bf16x8*)&A[(size_t)(m0 + row) * lda + k0 + c8 * 8];
            }
        }
        if constexpr (B32) {
            const float* B = (const float*)Bp;
#pragma unroll
            for (int i = 0; i < 4; ++i) {
                int idx = i * 256 + t, row = idx >> 3, c4 = idx & 7;
                rb32[i] = *(const float4*)&B[(size_t)(n0 + row) * K + k0 + c4 * 4];
            }
        } else {
            const unsigned short* B = (const unsigned short*)Bp;
#pragma unroll
            for (int i = 0; i < 2; ++i) {
                int idx = i * 256 + t, row = idx >> 2, c8 = idx & 3;
                rb16[i] = *(const bf16x8*)&B[(size_t)(n0 + row) * K + k0 + c8 * 8];
            }
        }
        __syncthreads();
        if constexpr (A32) {
#pragma unroll
            for (int i = 0; i < 4; ++i) {
                int idx = i * 256 + t, row = idx >> 3, c4 = idx & 7;
                uint2 p = { pack2(ra32[i].x, ra32[i].y), pack2(ra32[i].z, ra32[i].w) };
                *(uint2*)&As[row * 40 + c4 * 4] = p;
            }
        } else {
#pragma unroll
            for (int i = 0; i < 2; ++i) {
                int idx = i * 256 + t, row = idx >> 2, c8 = idx & 3;
                *(bf16x8*)&As[row * 40 + c8 * 8] = ra16[i];
            }
        }
        if constexpr (B32) {
#pragma unroll
            for (int i = 0; i < 4; ++i) {
                int idx = i * 256 + t, row = idx >> 3, c4 = idx & 7;
                uint2 p = { pack2(rb32[i].x, rb32[i].y), pack2(rb32[i].z, rb32[i].w) };
                *(uint2*)&Bs[row * 40 + c4 * 4] = p;
            }
        } else {
#pragma unroll
            for (int i = 0; i < 2; ++i) {
                int idx = i * 256 + t, row = idx >> 2, c8 = idx & 3;
                *(bf16x8*)&Bs[row * 40 + c8 * 8] = rb16[i];
            }
        }
        __syncthreads();
        bf16x8 af[4], bfr[4];
#pragma unroll
        for (int i = 0; i < 4; ++i) {
            af[i]  = *(const bf16x8*)&As[(wm * 64 + i * 16 + lr) * 40 + kc * 8];
            bfr[i] = *(const bf16x8*)&Bs[(wn * 64 + i * 16 + lr) * 40 + kc * 8];
        }
#pragma unroll
        for (int mi = 0; mi < 4; ++mi)
#pragma unroll
            for (int ni = 0; ni < 4; ++ni)
                acc[mi][ni] = __builtin_amdgcn_mfma_f32_16x16x32_bf16(af[mi], bfr[ni], acc[mi][ni], 0, 0, 0);
    }
    const int rb0 = kc * 4;
#pragma unroll
    for (int mi = 0; mi < 4; ++mi) {
#pragma unroll
        for (int ni = 0; ni < 4; ++ni) {
            int col = n0 + wn * 64 + ni * 16 + lr;
            float badd = HAS_BIAS ? bias[col] : 0.0f;
#pragma unroll
            for (int r = 0; r < 4; ++r) {
                int row = m0 + wm * 64 + mi * 16 + rb0 + r;
                size_t off = TRANS_C ? ((size_t)col * ldc + row) : ((size_t)row * ldc + col);
                if (C32) ((float*)Cp)[off] = acc[mi][ni][r] + badd;
                else     ((unsigned short*)Cp)[off] = f2bf(acc[mi][ni][r] + badd);
            }
        }
    }
}

__global__ __launch_bounds__(256, 2)
void attn_slow(unsigned short* __restrict__ qk, const unsigned short* __restrict__ vt) {
    __shared__ __align__(16) unsigned short Ks[64 * 136];
    __shared__ __align__(16) unsigned short Vs[128 * 72];
    __shared__ __align__(16) unsigned short Ps[4 * 32 * 72];
    const int t = threadIdx.x, lane = t & 63, w = t >> 6;
    const int h = blockIdx.y, q0 = blockIdx.x * 128;
    const int lr = lane & 15, kc = lane >> 4;
    const float scale = 0.08838834764831845f;

    bf16x8 aq[2][4];
#pragma unroll
    for (int mf = 0; mf < 2; ++mf)
#pragma unroll
        for (int ks = 0; ks < 4; ++ks)
            aq[mf][ks] = *(const bf16x8*)&qk[(size_t)(q0 + w * 32 + mf * 16 + lr) * 6144 + h * 128 + ks * 32 + kc * 8];

    f32x4 o[2][8] = {};
    float mst[2][4], lst[2][4];
#pragma unroll
    for (int mf = 0; mf < 2; ++mf)
#pragma unroll
        for (int r = 0; r < 4; ++r) { mst[mf][r] = -1e30f; lst[mf][r] = 0.0f; }

    unsigned short* Pw = &Ps[w * 32 * 72];

    for (int kb = 0; kb < 2048; kb += 64) {
        bf16x8 rk[4], rv[4];
#pragma unroll
        for (int i = 0; i < 4; ++i) {
            int idx = i * 256 + t;
            { int row = idx >> 4, c8 = idx & 15;
              rk[i] = *(const bf16x8*)&qk[(size_t)(kb + row) * 6144 + 3072 + h * 128 + c8 * 8]; }
            { int row = idx >> 3, c8 = idx & 7;
              rv[i] = *(const bf16x8*)&vt[(size_t)(h * 128 + row) * 2048 + kb + c8 * 8]; }
        }
        __syncthreads();
#pragma unroll
        for (int i = 0; i < 4; ++i) {
            int idx = i * 256 + t;
            { int row = idx >> 4, c8 = idx & 15; *(bf16x8*)&Ks[row * 136 + c8 * 8] = rk[i]; }
            { int row = idx >> 3, c8 = idx & 7;  *(bf16x8*)&Vs[row * 72 + c8 * 8] = rv[i]; }
        }
        __syncthreads();

        f32x4 s[2][4] = {};
#pragma unroll
        for (int nt = 0; nt < 4; ++nt) {
            int rkr = nt * 16 + lr;
#pragma unroll
            for (int ks = 0; ks < 4; ++ks) {
                bf16x8 bk = *(const bf16x8*)&Ks[rkr * 136 + (ks * 4 + kc) * 8];
#pragma unroll
                for (int mf = 0; mf < 2; ++mf)
                    s[mf][nt] = __builtin_amdgcn_mfma_f32_16x16x32_bf16(aq[mf][ks], bk, s[mf][nt], 0, 0, 0);
            }
        }
#pragma unroll
        for (int mf = 0; mf < 2; ++mf)
#pragma unroll
            for (int nt = 0; nt < 4; ++nt)
#pragma unroll
                for (int r = 0; r < 4; ++r) s[mf][nt][r] *= scale;

#pragma unroll
        for (int mf = 0; mf < 2; ++mf) {
#pragma unroll
            for (int r = 0; r < 4; ++r) {
                float vmax = fmaxf(fmaxf(s[mf][0][r], s[mf][1][r]), fmaxf(s[mf][2][r], s[mf][3][r]));
#pragma unroll
                for (int off = 8; off >= 1; off >>= 1) vmax = fmaxf(vmax, __shfl_xor(vmax, off));
                float mn = fmaxf(mst[mf][r], vmax);
                float al = __expf(mst[mf][r] - mn);
                mst[mf][r] = mn;
                float ps = 0.0f;
#pragma unroll
                for (int nt = 0; nt < 4; ++nt) {
                    float p = __expf(s[mf][nt][r] - mn);
                    s[mf][nt][r] = p;
                    ps += p;
                }
#pragma unroll
                for (int off = 8; off >= 1; off >>= 1) ps += __shfl_xor(ps, off);
                lst[mf][r] = lst[mf][r] * al + ps;
#pragma unroll
                for (int dt = 0; dt < 8; ++dt) o[mf][dt][r] *= al;
            }
        }

#pragma unroll
        for (int mf = 0; mf < 2; ++mf)
#pragma unroll
            for (int nt = 0; nt < 4; ++nt)
#pragma unroll
                for (int r = 0; r < 4; ++r)
                    Pw[(mf * 16 + kc * 4 + r) * 72 + nt * 16 + lr] = f2bf(s[mf][nt][r]);

#pragma unroll
        for (int ks2 = 0; ks2 < 2; ++ks2) {
            bf16x8 ap[2];
#pragma unroll
            for (int mf = 0; mf < 2; ++mf)
                ap[mf] = *(const bf16x8*)&Pw[(mf * 16 + lr) * 72 + (ks2 * 4 + kc) * 8];
#pragma unroll
            for (int dt = 0; dt < 8; ++dt) {
                bf16x8 bv = *(const bf16x8*)&Vs[(dt * 16 + lr) * 72 + (ks2 * 4 + kc) * 8];
#pragma unroll
                for (int mf = 0; mf < 2; ++mf)
                    o[mf][dt] = __builtin_amdgcn_mfma_f32_16x16x32_bf16(ap[mf], bv, o[mf][dt], 0, 0, 0);
            }
        }
        __syncthreads();
    }

#pragma unroll
    for (int mf = 0; mf < 2; ++mf)
#pragma unroll
        for (int dt = 0; dt < 8; ++dt)
#pragma unroll
            for (int r = 0; r < 4; ++r) {
                int row = q0 + w * 32 + mf * 16 + kc * 4 + r;
                qk[(size_t)row * 6144 + h * 128 + dt * 16 + lr] = f2bf(o[mf][dt][r] / lst[mf][r]);
            }
}

__global__ void fill_two(float* p, int n) {
    int i = blockIdx.x * 256 + threadIdx.x;
    if (i < n) p[i] = 2.0f;
}

// ---------------------------------------------------------------------------
// Fast path (ws >= 120 MiB), shorts offsets:
//   xb 0 | wqkvb 6291456 | wprojb 34603008 | qk 44040192 | vt 56623104
// Slow path: round-4 layout (qk @0, vt @12582912), peak 36 MiB.
// ---------------------------------------------------------------------------
extern "C" void kernel_launch(void* const* d_in, const int* in_sizes, int n_in,
                              void* d_out, int out_size, void* d_ws, size_t ws_size,
                              hipStream_t stream) {
    const float* x       = (const float*)d_in[0];
    const float* pe      = (const float*)d_in[1];
    const float* w_qkv   = (const float*)d_in[2];
    const float* q_scale = (const float*)d_in[3];
    const float* k_scale = (const float*)d_in[4];
    const float* w_proj  = (const float*)d_in[5];
    const float* b_proj  = (const float*)d_in[6];
    float* out = (float*)d_out;

    if (ws_size >= 125829120ull) {           // ---- fast path ----
        unsigned short* ws     = (unsigned short*)d_ws;
        unsigned short* xb     = ws;
        unsigned short* wqkvb  = ws + 6291456;
        unsigned short* wprojb = ws + 34603008;
        unsigned short* qk     = ws + 44040192;
        unsigned short* vt     = ws + 56623104;

        cvt_all<<<21504, 256, 0, stream>>>((const float4*)x, (const float4*)w_qkv,
                                           (const float4*)w_proj, (uint4*)xb);

        gemm_qkv<<<dim3(36, 16), 256, 0, stream>>>(xb, wqkvb, qk, vt);
        attn2<<<dim3(24, 16), 256, 0, stream>>>(qk, vt, pe, q_scale, k_scale);
        gemm_proj<<<dim3(24, 16), 256, 0, stream>>>(qk, wprojb, b_proj, out);
        return;
    }

    if (ws_size < 37748736ull) {             // ---- can't run at all ----
        fill_two<<<(6291456 + 255) / 256, 256, 0, stream>>>(out, 6291456);
        return;
    }

    // ---- slow path (round 4, proven) ----
    unsigned short* qk = (unsigned short*)d_ws;
    unsigned short* vt = qk + 12582912;

    gemm_bt<true, true, false, false, false><<<dim3(16, 48), 256, 0, stream>>>(
        x, w_qkv, nullptr, qk, 2048, 6144, 3072, 3072, 6144);
    norm_rope<<<24576, 256, 0, stream>>>(qk, pe, q_scale, k_scale);
    gemm_bt<true, true, false, false, true><<<dim3(16, 24), 256, 0, stream>>>(
        x, w_qkv + (size_t)6144 * 3072, nullptr, vt, 2048, 3072, 3072, 3072, 2048);
    attn_slow<<<dim3(16, 24), 256, 0, stream>>>(qk, vt);
    gemm_bt<false, true, true, true, false><<<dim3(16, 24), 256, 0, stream>>>(
        qk, w_proj, b_proj, out, 2048, 3072, 3072, 6144, 3072);
}

// Round 10
// 566.170 us; speedup vs baseline: 1.4925x; 1.4925x over previous
//
#include <hip/hip_runtime.h>

typedef __attribute__((ext_vector_type(8))) __bf16 bf16x8;
typedef __attribute__((ext_vector_type(4))) float f32x4;

typedef __attribute__((address_space(1))) void gvoid;
typedef __attribute__((address_space(3))) void lvoid;

__device__ __forceinline__ float bf2f(unsigned int u) {
    union { unsigned int u; float f; } v; v.u = u << 16; return v.f;
}
__device__ __forceinline__ unsigned short f2bf(float f) {
    union { float f; unsigned int u; } v; v.f = f;
    unsigned int r = v.u + 0x7fffu + ((v.u >> 16) & 1u);
    return (unsigned short)(r >> 16);
}
__device__ __forceinline__ unsigned int pack2(float a, float b) {
    return (unsigned int)f2bf(a) | ((unsigned int)f2bf(b) << 16);
}
__device__ __forceinline__ void async16(const void* g, void* l) {
    __builtin_amdgcn_global_load_lds((gvoid*)g, (lvoid*)l, 16, 0, 0);
}
// 2^x via v_exp_f32 (native). __exp2f is NOT declared in this env's headers.
__device__ __forceinline__ float exp2f_hw(float x) {
    return __builtin_amdgcn_exp2f(x);
}

// sum of squares of 8 bf16 (fp32 accumulation)
__device__ __forceinline__ float ssq8(bf16x8 v) {
    const unsigned int* u = (const unsigned int*)&v;
    float s = 0.0f;
#pragma unroll
    for (int j = 0; j < 4; ++j) {
        float x0 = bf2f(u[j] & 0xffffu), x1 = bf2f(u[j] >> 16);
        s += x0 * x0 + x1 * x1;
    }
    return s;
}
// RMSNorm(+scale)+RoPE applied to 8 bf16 (4 rope pairs, cols even-aligned).
// sc -> scale[gc..gc+7]; per -> &pe[(l*64 + gc/2)*4] (4 consecutive float4).
__device__ __forceinline__ bf16x8 normrope8(bf16x8 v, float rr,
                                            const float* __restrict__ sc,
                                            const float* __restrict__ per) {
    const unsigned int* u = (const unsigned int*)&v;
    bf16x8 out;
    unsigned int* ou = (unsigned int*)&out;
#pragma unroll
    for (int j = 0; j < 4; ++j) {
        float x0 = bf2f(u[j] & 0xffffu), x1 = bf2f(u[j] >> 16);
        float y0 = x0 * rr * sc[2 * j], y1 = x1 * rr * sc[2 * j + 1];
        float4 p4 = *(const float4*)(per + 4 * j);
        ou[j] = pack2(p4.x * y0 + p4.y * y1, p4.z * y0 + p4.w * y1);
    }
    return out;
}

// ============================ FAST PATH ====================================

// Fused fp32->bf16 convert of all three tensors in ONE launch (dst regions
// are contiguous in ws: xb @0 | wqkvb @786432 | wprojb @4325376, uint4 units).
__global__ __launch_bounds__(256)
void cvt_all(const float4* __restrict__ x, const float4* __restrict__ wqkv,
             const float4* __restrict__ wproj, uint4* __restrict__ dst) {
    int i = blockIdx.x * 256 + threadIdx.x;
    const float4* s; uint4* d; int off;
    if (i < 786432)       { s = x;     d = dst;           off = i; }
    else if (i < 4325376) { s = wqkv;  d = dst + 786432;  off = i - 786432; }
    else if (i < 5505024) { s = wproj; d = dst + 4325376; off = i - 4325376; }
    else return;
    float4 a = s[2 * off], b = s[2 * off + 1];
    uint4 o;
    o.x = pack2(a.x, a.y); o.y = pack2(a.z, a.w);
    o.z = pack2(b.x, b.y); o.w = pack2(b.z, b.w);
    d[off] = o;
}

// ---- 128x128 ring core — retained for gemm_proj (round-3 proven) ----
#define GEMM_CORE(A_, lda_, B_, ldb_, K_)                                        \
    __shared__ __align__(16) unsigned short As[4][4096];                         \
    __shared__ __align__(16) unsigned short Bs[4][4096];                         \
    const int t = threadIdx.x, lane = t & 63;                                    \
    const int wm = t >> 7, wn = (t >> 6) & 1;                                    \
    const int lr = lane & 15, kc = lane >> 4;                                    \
    const int NK = (K_) / 32;                                                    \
    const int e0 = t * 8, e1 = (256 + t) * 8;                                    \
    const int r0 = e0 >> 5, c0 = (e0 >> 3) & 3;                                  \
    const int r1 = e1 >> 5, c1 = (e1 >> 3) & 3;                                  \
    const int g0 = (c0 ^ ((r0 >> 1) & 3)) * 8;                                   \
    const int g1 = (c1 ^ ((r1 >> 1) & 3)) * 8;                                   \
    const unsigned short* Ag0 = &(A_)[(size_t)(m0 + r0) * (lda_) + g0];          \
    const unsigned short* Ag1 = &(A_)[(size_t)(m0 + r1) * (lda_) + g1];          \
    const unsigned short* Bg0 = &(B_)[(size_t)(n0 + r0) * (ldb_) + g0];          \
    const unsigned short* Bg1 = &(B_)[(size_t)(n0 + r1) * (ldb_) + g1];          \
    f32x4 acc[4][4] = {};                                                        \
    RSTAGE(0) RSTAGE(1) RSTAGE(2)                                                \
    asm volatile("s_waitcnt vmcnt(8)" ::: "memory");                             \
    __builtin_amdgcn_s_barrier();                                                \
    for (int kt = 0; kt < NK; ++kt) {                                            \
        const int sl = kt & 3;                                                   \
        bf16x8 af[4], bfr[4];                                                    \
        _Pragma("unroll")                                                        \
        for (int i = 0; i < 4; ++i) {                                            \
            int ra = wm * 64 + i * 16 + lr;                                      \
            int rb = wn * 64 + i * 16 + lr;                                      \
            af[i]  = *(const bf16x8*)&As[sl][ra * 32 + ((kc ^ ((ra >> 1) & 3)) * 8)]; \
            bfr[i] = *(const bf16x8*)&Bs[sl][rb * 32 + ((kc ^ ((rb >> 1) & 3)) * 8)]; \
        }                                                                        \
        if (kt + 3 < NK) RSTAGE(kt + 3)                                          \
        asm volatile("s_waitcnt lgkmcnt(0)" ::: "memory");                       \
        __builtin_amdgcn_sched_barrier(0);                                       \
        __builtin_amdgcn_s_setprio(1);                                           \
        _Pragma("unroll")                                                        \
        for (int mi = 0; mi < 4; ++mi)                                           \
            _Pragma("unroll")                                                    \
            for (int ni = 0; ni < 4; ++ni)                                       \
                acc[mi][ni] = __builtin_amdgcn_mfma_f32_16x16x32_bf16(           \
                    af[mi], bfr[ni], acc[mi][ni], 0, 0, 0);                      \
        __builtin_amdgcn_s_setprio(0);                                           \
        if (kt + 3 < NK)      { asm volatile("s_waitcnt vmcnt(8)" ::: "memory"); } \
        else if (kt + 2 < NK) { asm volatile("s_waitcnt vmcnt(4)" ::: "memory"); } \
        else if (kt + 1 < NK) { asm volatile("s_waitcnt vmcnt(0)" ::: "memory"); } \
        __builtin_amdgcn_s_barrier();                                            \
    }

#define RSTAGE(kt_) { const int s_ = (kt_) & 3; const size_t k_ = (size_t)(kt_) * 32; \
        async16(Ag0 + k_, &As[s_][e0]); async16(Ag1 + k_, &As[s_][e1]);               \
        async16(Bg0 + k_, &Bs[s_][e0]); async16(Bg1 + k_, &Bs[s_][e1]); }

// Fused QKV GEMM — EXACT round-4 config (fastest measured: ~180 µs).
// 128x256 tile, 4 waves x [128m x 64n], BK=32, 3-slot LDS ring (72 KiB,
// 2 blocks/CU), depth-2 prefetch, counted vmcnt(6). No XCD remap.
// A=xb[2048][3072], B=wqkvb[9216][3072].
// cols <6144 -> qk[row][col]; cols >=6144 -> vt[col-6144][row] (V transposed).
__global__ __launch_bounds__(256, 2)
void gemm_qkv(const unsigned short* __restrict__ A, const unsigned short* __restrict__ B,
              unsigned short* __restrict__ qk, unsigned short* __restrict__ vt) {
    __shared__ __align__(16) unsigned short As[3][4096];   // 128 x 32
    __shared__ __align__(16) unsigned short Bs[3][8192];   // 256 x 32
    const int n0 = blockIdx.x * 256, m0 = blockIdx.y * 128;
    const int t = threadIdx.x, lane = t & 63, w = t >> 6;
    const int lr = lane & 15, kc = lane >> 4;
    const int NK = 96;                        // 3072 / 32

    const int ea0 = t * 8,         ra0 = ea0 >> 5, ca0 = (ea0 >> 3) & 3;
    const int ea1 = (256 + t) * 8, ra1 = ea1 >> 5, ca1 = (ea1 >> 3) & 3;
    const int ga0 = (ca0 ^ ((ra0 >> 1) & 3)) * 8;
    const int ga1 = (ca1 ^ ((ra1 >> 1) & 3)) * 8;
    const unsigned short* Ag0 = &A[(size_t)(m0 + ra0) * 3072 + ga0];
    const unsigned short* Ag1 = &A[(size_t)(m0 + ra1) * 3072 + ga1];
    int eb[4];
    const unsigned short* Bg[4];
#pragma unroll
    for (int i = 0; i < 4; ++i) {
        eb[i] = (i * 256 + t) * 8;
        int rb = eb[i] >> 5, cb = (eb[i] >> 3) & 3;
        int gb = (cb ^ ((rb >> 1) & 3)) * 8;
        Bg[i] = &B[(size_t)(n0 + rb) * 3072 + gb];
    }

#define QSTAGE(kt_) { const int s_ = (kt_) % 3; const size_t k_ = (size_t)(kt_) * 32; \
        async16(Ag0 + k_, &As[s_][ea0]); async16(Ag1 + k_, &As[s_][ea1]);             \
        async16(Bg[0] + k_, &Bs[s_][eb[0]]); async16(Bg[1] + k_, &Bs[s_][eb[1]]);     \
        async16(Bg[2] + k_, &Bs[s_][eb[2]]); async16(Bg[3] + k_, &Bs[s_][eb[3]]); }

    f32x4 acc[8][4] = {};

    QSTAGE(0) QSTAGE(1)
    asm volatile("s_waitcnt vmcnt(6)" ::: "memory");
    __builtin_amdgcn_s_barrier();

    for (int kt = 0; kt < NK; ++kt) {
        const int sl = kt % 3;
        bf16x8 af[8], bfr[4];
#pragma unroll
        for (int i = 0; i < 8; ++i) {
            int ra = i * 16 + lr;
            af[i] = *(const bf16x8*)&As[sl][ra * 32 + ((kc ^ ((ra >> 1) & 3)) * 8)];
        }
#pragma unroll
        for (int i = 0; i < 4; ++i) {
            int rb = w * 64 + i * 16 + lr;
            bfr[i] = *(const bf16x8*)&Bs[sl][rb * 32 + ((kc ^ ((rb >> 1) & 3)) * 8)];
        }
        if (kt + 2 < NK) QSTAGE(kt + 2)
        asm volatile("s_waitcnt lgkmcnt(0)" ::: "memory");
        __builtin_amdgcn_sched_barrier(0);
        __builtin_amdgcn_s_setprio(1);
#pragma unroll
        for (int mi = 0; mi < 8; ++mi)
#pragma unroll
            for (int ni = 0; ni < 4; ++ni)
                acc[mi][ni] = __builtin_amdgcn_mfma_f32_16x16x32_bf16(
                    af[mi], bfr[ni], acc[mi][ni], 0, 0, 0);
        __builtin_amdgcn_s_setprio(0);
        if (kt + 2 < NK) { asm volatile("s_waitcnt vmcnt(6)" ::: "memory"); }
        else             { asm volatile("s_waitcnt vmcnt(0)" ::: "memory"); }
        __builtin_amdgcn_s_barrier();
    }
#undef QSTAGE

    const int rb0 = kc * 4;
#pragma unroll
    for (int mi = 0; mi < 8; ++mi)
#pragma unroll
        for (int ni = 0; ni < 4; ++ni) {
            int col = n0 + w * 64 + ni * 16 + lr;
#pragma unroll
            for (int r = 0; r < 4; ++r) {
                int row = m0 + mi * 16 + rb0 + r;
                unsigned short v = f2bf(acc[mi][ni][r]);
                if (col < 6144) qk[(size_t)row * 6144 + col] = v;
                else            vt[(size_t)(col - 6144) * 2048 + row] = v;
            }
        }
}

// Proj GEMM: A=qk(attn out, lda 6144), B=wprojb[3072][3072], fp32 out + bias.
__global__ __launch_bounds__(256, 2)
void gemm_proj(const unsigned short* __restrict__ A, const unsigned short* __restrict__ B,
               const float* __restrict__ bias, float* __restrict__ out) {
    const int n0 = blockIdx.x * 128, m0 = blockIdx.y * 128;
    GEMM_CORE(A, 6144, B, 3072, 3072)
    const int rb0 = kc * 4;
#pragma unroll
    for (int mi = 0; mi < 4; ++mi)
#pragma unroll
        for (int ni = 0; ni < 4; ++ni) {
            int col = n0 + wn * 64 + ni * 16 + lr;
            float badd = bias[col];
#pragma unroll
            for (int r = 0; r < 4; ++r) {
                int row = m0 + wm * 64 + mi * 16 + rb0 + r;
                out[(size_t)row * 3072 + col] = acc[mi][ni][r] + badd;
            }
        }
}

// K-only RMSNorm+RoPE on qk cols 3072.. (Q is fused into attn2; K kept as a
// standalone pass — ROUND-9 POST-MORTEM: fusing K's transform into attn2's
// prefetch path exploded live ranges -> scratch spill (283 MB writes, 415 µs).
// Q-only fusion is pre-loop/transient and safe.)
__global__ __launch_bounds__(256)
void norm_rope_k(unsigned short* __restrict__ qk, const float* __restrict__ pe,
                 const float* __restrict__ k_scale) {
    const int wid = threadIdx.x >> 6, lane = threadIdx.x & 63;
    int pid = blockIdx.x * 4 + wid;            // 0..49151
    const int h = pid >> 11, l = pid & 2047;

    unsigned short* src = qk + (size_t)l * 6144 + 3072 + h * 128 + lane * 2;
    unsigned int xu = *(const unsigned int*)src;
    float x0 = bf2f(xu & 0xffffu), x1 = bf2f(xu >> 16);
    float ss = x0 * x0 + x1 * x1;
#pragma unroll
    for (int off = 32; off >= 1; off >>= 1) ss += __shfl_xor(ss, off);
    float rr = rsqrtf(ss * (1.0f / 128.0f) + 1e-6f);

    float2 s2 = *(const float2*)(k_scale + lane * 2);
    float y0 = x0 * rr * s2.x;
    float y1 = x1 * rr * s2.y;

    float4 p4 = *(const float4*)(pe + ((size_t)l * 64 + lane) * 4);
    float o0 = p4.x * y0 + p4.y * y1;
    float o1 = p4.z * y0 + p4.w * y1;

    *(unsigned int*)src = pack2(o0, o1);
}

// Flash attention v6 = ROUND-8 body (proven 566.6 µs state) + Q-normrope
// fused at block start (pre-loop, in-register, transient temps — safe half
// of the round-9 fusion). K arrives pre-transformed via norm_rope_k.
// Deferred reductions (2 ballots/iter, final sum reduce once) kept.
// Grid (24,16)=384 blocks, 48KB LDS -> 3 blocks/CU. T14 prefetch kept.
__global__ __launch_bounds__(256, 2)
void attn2(unsigned short* __restrict__ qk, const unsigned short* __restrict__ vt,
           const float* __restrict__ pe, const float* __restrict__ q_scale) {
    __shared__ __align__(16) unsigned short Ks[64 * 128];
    __shared__ __align__(16) unsigned short Vs[128 * 64];
    __shared__ __align__(16) unsigned short Ps[4 * 32 * 64];
    const int t = threadIdx.x, lane = t & 63, w = t >> 6;
    const int h = blockIdx.x, qblk = blockIdx.y * 128;
    const int lr = lane & 15, kc = lane >> 4;
    const float sc2 = 0.08838834764831845f * 1.4426950408889634f; // scale*log2e
    const float THR = 62.7f;                                      // 8 / sc2

    // ---- load Q fragments and apply RMSNorm+RoPE (once per block) ----
    bf16x8 aq[2][4];
#pragma unroll
    for (int mf = 0; mf < 2; ++mf)
#pragma unroll
        for (int ks = 0; ks < 4; ++ks)
            aq[mf][ks] = *(const bf16x8*)&qk[(size_t)(qblk + w * 32 + mf * 16 + lr) * 6144 + h * 128 + ks * 32 + kc * 8];
#pragma unroll
    for (int mf = 0; mf < 2; ++mf) {
        float ss = 0.0f;
#pragma unroll
        for (int ks = 0; ks < 4; ++ks) ss += ssq8(aq[mf][ks]);
        ss += __shfl_xor(ss, 16); ss += __shfl_xor(ss, 32);   // 4 kc-groups = 128 elems
        float rr = rsqrtf(ss * (1.0f / 128.0f) + 1e-6f);
        int lq = qblk + w * 32 + mf * 16 + lr;
#pragma unroll
        for (int ks = 0; ks < 4; ++ks) {
            int c0 = ks * 32 + kc * 8;
            aq[mf][ks] = normrope8(aq[mf][ks], rr, q_scale + c0,
                                   pe + ((size_t)lq * 64 + (c0 >> 1)) * 4);
        }
    }

    f32x4 o[2][8] = {};
    float mst[2][4], lpart[2][4];
#pragma unroll
    for (int mf = 0; mf < 2; ++mf)
#pragma unroll
        for (int r = 0; r < 4; ++r) { mst[mf][r] = -1e30f; lpart[mf][r] = 0.0f; }

    unsigned short* Pw = &Ps[w * 2048];

    // prologue: stage tile kb=0 via async16 (drained by first __syncthreads)
#pragma unroll
    for (int i = 0; i < 4; ++i) {
        int e = (i * 256 + t) * 8;
        {   // K tile [64 keys][128 d]
            int row = e >> 7, c8 = (e >> 3) & 15;
            int gc = (c8 ^ (row & 15)) * 8;
            async16(&qk[(size_t)row * 6144 + 3072 + h * 128 + gc], &Ks[e]);
        }
        {   // V^T tile [128 d][64 keys]
            int row = e >> 6, c8 = (e >> 3) & 7;
            int gc = (c8 ^ (row & 7)) * 8;
            async16(&vt[(size_t)(h * 128 + row) * 2048 + gc], &Vs[e]);
        }
    }

    for (int kb = 0; kb < 2048; kb += 64) {
        __syncthreads();                 // tile kb present in Ks/Vs

        // T14: issue register prefetch of tile kb+64 (hidden under compute)
        bf16x8 pk[4], pv[4];
        const bool pf = (kb + 64) < 2048;
        if (pf) {
#pragma unroll
            for (int i = 0; i < 4; ++i) {
                int e = (i * 256 + t) * 8;
                {   int row = e >> 7, c8 = (e >> 3) & 15;
                    int gc = (c8 ^ (row & 15)) * 8;
                    pk[i] = *(const bf16x8*)&qk[(size_t)(kb + 64 + row) * 6144 + 3072 + h * 128 + gc];
                }
                {   int row = e >> 6, c8 = (e >> 3) & 7;
                    int gc = (c8 ^ (row & 7)) * 8;
                    pv[i] = *(const bf16x8*)&vt[(size_t)(h * 128 + row) * 2048 + kb + 64 + gc];
                }
            }
        }

        // S = Q K^T  (each bk read feeds both mf halves)
        f32x4 s[2][4] = {};
#pragma unroll
        for (int nt = 0; nt < 4; ++nt) {
            int rk = nt * 16 + lr;
#pragma unroll
            for (int ks = 0; ks < 4; ++ks) {
                int ck = ks * 4 + kc;
                bf16x8 bk = *(const bf16x8*)&Ks[rk * 128 + ((ck ^ (rk & 15)) * 8)];
#pragma unroll
                for (int mf = 0; mf < 2; ++mf)
                    s[mf][nt] = __builtin_amdgcn_mfma_f32_16x16x32_bf16(aq[mf][ks], bk, s[mf][nt], 0, 0, 0);
            }
        }

        // softmax, exp2 domain, fully deferred reductions
#pragma unroll
        for (int mf = 0; mf < 2; ++mf) {
            float lm[4]; bool need = false;
#pragma unroll
            for (int r = 0; r < 4; ++r) {
                lm[r] = fmaxf(fmaxf(s[mf][0][r], s[mf][1][r]), fmaxf(s[mf][2][r], s[mf][3][r]));
                need = need || (lm[r] > mst[mf][r] + THR);
            }
            if (__ballot(need) != 0ull) {      // rare; always on first tile
#pragma unroll
                for (int r = 0; r < 4; ++r) {
                    float vmax = lm[r];
#pragma unroll
                    for (int off = 8; off >= 1; off >>= 1) vmax = fmaxf(vmax, __shfl_xor(vmax, off));
                    float mn = fmaxf(mst[mf][r], vmax);
                    float al = exp2f_hw((mst[mf][r] - mn) * sc2);
                    mst[mf][r] = mn;
                    lpart[mf][r] *= al;
#pragma unroll
                    for (int dt = 0; dt < 8; ++dt) o[mf][dt][r] *= al;
                }
            }
#pragma unroll
            for (int r = 0; r < 4; ++r) {
                float ps = 0.0f;
#pragma unroll
                for (int nt = 0; nt < 4; ++nt) {
                    float p = exp2f_hw((s[mf][nt][r] - mst[mf][r]) * sc2);
                    s[mf][nt][r] = p;
                    ps += p;
                }
                lpart[mf][r] += ps;            // per-lane partial; no shuffles
            }
        }

        // P (C-layout) -> per-wave LDS [32 q][64 kk], chunk ^= (q&7)
#pragma unroll
        for (int mf = 0; mf < 2; ++mf)
#pragma unroll
            for (int nt = 0; nt < 4; ++nt) {
                int col = nt * 16 + lr;
                int chunk = col >> 3, cin = col & 7;
#pragma unroll
                for (int r = 0; r < 4; ++r) {
                    int q = mf * 16 + kc * 4 + r;
                    Pw[q * 64 + ((chunk ^ (q & 7)) * 8 + cin)] = f2bf(s[mf][nt][r]);
                }
            }

        // O += P @ V  (each bv read feeds both mf halves)
#pragma unroll
        for (int ks2 = 0; ks2 < 2; ++ks2) {
            int ck = ks2 * 4 + kc;
            bf16x8 ap[2];
#pragma unroll
            for (int mf = 0; mf < 2; ++mf) {
                int q = mf * 16 + lr;
                ap[mf] = *(const bf16x8*)&Pw[q * 64 + ((ck ^ (q & 7)) * 8)];
            }
#pragma unroll
            for (int dt = 0; dt < 8; ++dt) {
                int rv = dt * 16 + lr;
                bf16x8 bv = *(const bf16x8*)&Vs[rv * 64 + ((ck ^ (rv & 7)) * 8)];
#pragma unroll
                for (int mf = 0; mf < 2; ++mf)
                    o[mf][dt] = __builtin_amdgcn_mfma_f32_16x16x32_bf16(ap[mf], bv, o[mf][dt], 0, 0, 0);
            }
        }
        __syncthreads();                 // all reads of tile kb done

        if (pf) {
#pragma unroll
            for (int i = 0; i < 4; ++i) {
                int e = (i * 256 + t) * 8;
                *(bf16x8*)&Ks[e] = pk[i];
                *(bf16x8*)&Vs[e] = pv[i];
            }
        }
    }

    // final cross-lane reduction of lpart (once), then write
#pragma unroll
    for (int mf = 0; mf < 2; ++mf)
#pragma unroll
        for (int r = 0; r < 4; ++r) {
            float ps = lpart[mf][r];
#pragma unroll
            for (int off = 8; off >= 1; off >>= 1) ps += __shfl_xor(ps, off);
            lpart[mf][r] = ps;
        }
#pragma unroll
    for (int mf = 0; mf < 2; ++mf)
#pragma unroll
        for (int dt = 0; dt < 8; ++dt)
#pragma unroll
            for (int r = 0; r < 4; ++r) {
                int row = qblk + w * 32 + mf * 16 + kc * 4 + r;
                qk[(size_t)row * 6144 + h * 128 + dt * 16 + lr] = f2bf(o[mf][dt][r] / lpart[mf][r]);
            }
}

// ===================== SHARED (slow path only now) =========================

// In-place RMSNorm + RoPE on qk[2048][6144] bf16 (q cols 0..3071, k 3072+).
__global__ __launch_bounds__(256)
void norm_rope(unsigned short* __restrict__ qk, const float* __restrict__ pe,
               const float* __restrict__ q_scale, const float* __restrict__ k_scale) {
    const int wid = threadIdx.x >> 6, lane = threadIdx.x & 63;
    int pid = blockIdx.x * 4 + wid;
    const int isK = pid >= 49152;
    int p2 = isK ? pid - 49152 : pid;
    const int h = p2 >> 11, l = p2 & 2047;

    unsigned short* src = qk + (size_t)l * 6144 + (isK ? 3072 : 0) + h * 128 + lane * 2;
    unsigned int xu = *(const unsigned int*)src;
    float x0 = bf2f(xu & 0xffffu), x1 = bf2f(xu >> 16);
    float ss = x0 * x0 + x1 * x1;
#pragma unroll
    for (int off = 32; off >= 1; off >>= 1) ss += __shfl_xor(ss, off);
    float rr = rsqrtf(ss * (1.0f / 128.0f) + 1e-6f);

    const float* sc = isK ? k_scale : q_scale;
    float2 s2 = *(const float2*)(sc + lane * 2);
    float y0 = x0 * rr * s2.x;
    float y1 = x1 * rr * s2.y;

    float4 p4 = *(const float4*)(pe + ((size_t)l * 64 + lane) * 4);
    float o0 = p4.x * y0 + p4.y * y1;
    float o1 = p4.z * y0 + p4.w * y1;

    *(unsigned int*)src = pack2(o0, o1);
}

// ===================== SLOW PATH (round-4, proven) =========================

template <bool A32, bool B32, bool C32, bool HAS_BIAS, bool TRANS_C>
__global__ __launch_bounds__(256, 2)
void gemm_bt(const void* __restrict__ Ap, const void* __restrict__ Bp,
             const float* __restrict__ bias, void* __restrict__ Cp,
             int M, int N, int K, int lda, int ldc) {
    __shared__ __align__(16) unsigned short As[128 * 40];
    __shared__ __align__(16) unsigned short Bs[128 * 40];
    const int t = threadIdx.x, lane = t & 63;
    const int wm = t >> 7, wn = (t >> 6) & 1;
    const int m0 = blockIdx.x * 128, n0 = blockIdx.y * 128;
    const int lr = lane & 15, kc = lane >> 4;
    f32x4 acc[4][4] = {};

    for (int k0 = 0; k0 < K; k0 += 32) {
        float4 ra32[4], rb32[4];
        bf16x8 ra16[2], rb16[2];
        if constexpr (A32) {
            const float* A = (const float*)Ap;
#pragma unroll
            for (int i = 0; i < 4; ++i) {
                int idx = i * 256 + t, row = idx >> 3, c4 = idx & 7;
                ra32[i] = *(const float4*)&A[(size_t)(m0 + row) * lda + k0 + c4 * 4];
            }
        } else {
            const unsigned short* A = (const unsigned short*)Ap;
#pragma unroll
            for (int i = 0; i < 2; ++i) {
                int idx = i * 256 + t, row = idx >> 2, c8 = idx & 3;
                ra16[i] = *(const bf16x8*)&A[(size_t)(m0 + row) * lda + k0 + c8 * 8];
            }
        }
        if constexpr (B32) {
            const float* B = (const float*)Bp;
#pragma unroll
            for (int i = 0; i < 4; ++i) {
                int idx = i * 256 + t, row = idx >> 3, c4 = idx & 7;
                rb32[i] = *(const float4*)&B[(size_t)(n0 + row) * K + k0 + c4 * 4];
            }
        } else {
            const unsigned short* B = (const unsigned short*)Bp;
#pragma unroll
            for (int i = 0; i < 2; ++i) {
                int idx = i * 256 + t, row = idx >> 2, c8 = idx & 3;
                rb16[i] = *(const bf16x8*)&B[(size_t)(n0 + row) * K + k0 + c8 * 8];
            }
        }
        __syncthreads();
        if constexpr (A32) {
#pragma unroll
            for (int i = 0; i < 4; ++i) {
                int idx = i * 256 + t, row = idx >> 3, c4 = idx & 7;
                uint2 p = { pack2(ra32[i].x, ra32[i].y), pack2(ra32[i].z, ra32[i].w) };
                *(uint2*)&As[row * 40 + c4 * 4] = p;
            }
        } else {
#pragma unroll
            for (int i = 0; i < 2; ++i) {
                int idx = i * 256 + t, row = idx >> 2, c8 = idx & 3;
                *(bf16x8*)&As[row * 40 + c8 * 8] = ra16[i];
            }
        }
        if constexpr (B32) {
#pragma unroll
            for (int i = 0; i < 4; ++i) {
                int idx = i * 256 + t, row = idx >> 3, c4 = idx & 7;
                uint2 p = { pack2(rb32[i].x, rb32[i].y), pack2(rb32[i].z, rb32[i].w) };
                *(uint2*)&Bs[row * 40 + c4 * 4] = p;
            }
        } else {
#pragma unroll
            for (int i = 0; i < 2; ++i) {
                int idx = i * 256 + t, row = idx >> 2, c8 = idx & 3;
                *(bf16x8*)&Bs[row * 40 + c8 * 8] = rb16[i];
            }
        }
        __syncthreads();
        bf16x8 af[4], bfr[4];
#pragma unroll
        for (int i = 0; i < 4; ++i) {
            af[i]  = *(const bf16x8*)&As[(wm * 64 + i * 16 + lr) * 40 + kc * 8];
            bfr[i] = *(const bf16x8*)&Bs[(wn * 64 + i * 16 + lr) * 40 + kc * 8];
        }
#pragma unroll
        for (int mi = 0; mi < 4; ++mi)
#pragma unroll
            for (int ni = 0; ni < 4; ++ni)
                acc[mi][ni] = __builtin_amdgcn_mfma_f32_16x16x32_bf16(af[mi], bfr[ni], acc[mi][ni], 0, 0, 0);
    }
    const int rb0 = kc * 4;
#pragma unroll
    for (int mi = 0; mi < 4; ++mi) {
#pragma unroll
        for (int ni = 0; ni < 4; ++ni) {
            int col = n0 + wn * 64 + ni * 16 + lr;
            float badd = HAS_BIAS ? bias[col] : 0.0f;
#pragma unroll
            for (int r = 0; r < 4; ++r) {
                int row = m0 + wm * 64 + mi * 16 + rb0 + r;
                size_t off = TRANS_C ? ((size_t)col * ldc + row) : ((size_t)row * ldc + col);
                if (C32) ((float*)Cp)[off] = acc[mi][ni][r] + badd;
                else     ((unsigned short*)Cp)[off] = f2bf(acc[mi][ni][r] + badd);
            }
        }
    }
}

__global__ __launch_bounds__(256, 2)
void attn_slow(unsigned short* __restrict__ qk, const unsigned short* __restrict__ vt) {
    __shared__ __align__(16) unsigned short Ks[64 * 136];
    __shared__ __align__(16) unsigned short Vs[128 * 72];
    __shared__ __align__(16) unsigned short Ps[4 * 32 * 72];
    const int t = threadIdx.x, lane = t & 63, w = t >> 6;
    const int h = blockIdx.y, q0 = blockIdx.x * 128;
    const int lr = lane & 15, kc = lane >> 4;
    const float scale = 0.08838834764831845f;

    bf16x8 aq[2][4];
#pragma unroll
    for (int mf = 0; mf < 2; ++mf)
#pragma unroll
        for (int ks = 0; ks < 4; ++ks)
            aq[mf][ks] = *(const bf16x8*)&qk[(size_t)(q0 + w * 32 + mf * 16 + lr) * 6144 + h * 128 + ks * 32 + kc * 8];

    f32x4 o[2][8] = {};
    float mst[2][4], lst[2][4];
#pragma unroll
    for (int mf = 0; mf < 2; ++mf)
#pragma unroll
        for (int r = 0; r < 4; ++r) { mst[mf][r] = -1e30f; lst[mf][r] = 0.0f; }

    unsigned short* Pw = &Ps[w * 32 * 72];

    for (int kb = 0; kb < 2048; kb += 64) {
        bf16x8 rk[4], rv[4];
#pragma unroll
        for (int i = 0; i < 4; ++i) {
            int idx = i * 256 + t;
            { int row = idx >> 4, c8 = idx & 15;
              rk[i] = *(const bf16x8*)&qk[(size_t)(kb + row) * 6144 + 3072 + h * 128 + c8 * 8]; }
            { int row = idx >> 3, c8 = idx & 7;
              rv[i] = *(const bf16x8*)&vt[(size_t)(h * 128 + row) * 2048 + kb + c8 * 8]; }
        }
        __syncthreads();
#pragma unroll
        for (int i = 0; i < 4; ++i) {
            int idx = i * 256 + t;
            { int row = idx >> 4, c8 = idx & 15; *(bf16x8*)&Ks[row * 136 + c8 * 8] = rk[i]; }
            { int row = idx >> 3, c8 = idx & 7;  *(bf16x8*)&Vs[row * 72 + c8 * 8] = rv[i]; }
        }
        __syncthreads();

        f32x4 s[2][4] = {};
#pragma unroll
        for (int nt = 0; nt < 4; ++nt) {
            int rkr = nt * 16 + lr;
#pragma unroll
            for (int ks = 0; ks < 4; ++ks) {
                bf16x8 bk = *(const bf16x8*)&Ks[rkr * 136 + (ks * 4 + kc) * 8];
#pragma unroll
                for (int mf = 0; mf < 2; ++mf)
                    s[mf][nt] = __builtin_amdgcn_mfma_f32_16x16x32_bf16(aq[mf][ks], bk, s[mf][nt], 0, 0, 0);
            }
        }
#pragma unroll
        for (int mf = 0; mf < 2; ++mf)
#pragma unroll
            for (int nt = 0; nt < 4; ++nt)
#pragma unroll
                for (int r = 0; r < 4; ++r) s[mf][nt][r] *= scale;

#pragma unroll
        for (int mf = 0; mf < 2; ++mf) {
#pragma unroll
            for (int r = 0; r < 4; ++r) {
                float vmax = fmaxf(fmaxf(s[mf][0][r], s[mf][1][r]), fmaxf(s[mf][2][r], s[mf][3][r]));
#pragma unroll
                for (int off = 8; off >= 1; off >>= 1) vmax = fmaxf(vmax, __shfl_xor(vmax, off));
                float mn = fmaxf(mst[mf][r], vmax);
                float al = __expf(mst[mf][r] - mn);
                mst[mf][r] = mn;
                float ps = 0.0f;
#pragma unroll
                for (int nt = 0; nt < 4; ++nt) {
                    float p = __expf(s[mf][nt][r] - mn);
                    s[mf][nt][r] = p;
                    ps += p;
                }
#pragma unroll
                for (int off = 8; off >= 1; off >>= 1) ps += __shfl_xor(ps, off);
                lst[mf][r] = lst[mf][r] * al + ps;
#pragma unroll
                for (int dt = 0; dt < 8; ++dt) o[mf][dt][r] *= al;
            }
        }

#pragma unroll
        for (int mf = 0; mf < 2; ++mf)
#pragma unroll
            for (int nt = 0; nt < 4; ++nt)
#pragma unroll
                for (int r = 0; r < 4; ++r)
                    Pw[(mf * 16 + kc * 4 + r) * 72 + nt * 16 + lr] = f2bf(s[mf][nt][r]);

#pragma unroll
        for (int ks2 = 0; ks2 < 2; ++ks2) {
            bf16x8 ap[2];
#pragma unroll
            for (int mf = 0; mf < 2; ++mf)
                ap[mf] = *(const bf16x8*)&Pw[(mf * 16 + lr) * 72 + (ks2 * 4 + kc) * 8];
#pragma unroll
            for (int dt = 0; dt < 8; ++dt) {
                bf16x8 bv = *(const bf16x8*)&Vs[(dt * 16 + lr) * 72 + (ks2 * 4 + kc) * 8];
#pragma unroll
                for (int mf = 0; mf < 2; ++mf)
                    o[mf][dt] = __builtin_amdgcn_mfma_f32_16x16x32_bf16(ap[mf], bv, o[mf][dt], 0, 0, 0);
            }
        }
        __syncthreads();
    }

#pragma unroll
    for (int mf = 0; mf < 2; ++mf)
#pragma unroll
        for (int dt = 0; dt < 8; ++dt)
#pragma unroll
            for (int r = 0; r < 4; ++r) {
                int row = q0 + w * 32 + mf * 16 + kc * 4 + r;
                qk[(size_t)row * 6144 + h * 128 + dt * 16 + lr] = f2bf(o[mf][dt][r] / lst[mf][r]);
            }
}

__global__ void fill_two(float* p, int n) {
    int i = blockIdx.x * 256 + threadIdx.x;
    if (i < n) p[i] = 2.0f;
}

// ---------------------------------------------------------------------------
// Fast path (ws >= 120 MiB), shorts offsets:
//   xb 0 | wqkvb 6291456 | wprojb 34603008 | qk 44040192 | vt 56623104
// Slow path: round-4 layout (qk @0, vt @12582912), peak 36 MiB.
// ---------------------------------------------------------------------------
extern "C" void kernel_launch(void* const* d_in, const int* in_sizes, int n_in,
                              void* d_out, int out_size, void* d_ws, size_t ws_size,
                              hipStream_t stream) {
    const float* x       = (const float*)d_in[0];
    const float* pe      = (const float*)d_in[1];
    const float* w_qkv   = (const float*)d_in[2];
    const float* q_scale = (const float*)d_in[3];
    const float* k_scale = (const float*)d_in[4];
    const float* w_proj  = (const float*)d_in[5];
    const float* b_proj  = (const float*)d_in[6];
    float* out = (float*)d_out;

    if (ws_size >= 125829120ull) {           // ---- fast path ----
        unsigned short* ws     = (unsigned short*)d_ws;
        unsigned short* xb     = ws;
        unsigned short* wqkvb  = ws + 6291456;
        unsigned short* wprojb = ws + 34603008;
        unsigned short* qk     = ws + 44040192;
        unsigned short* vt     = ws + 56623104;

        cvt_all<<<21504, 256, 0, stream>>>((const float4*)x, (const float4*)w_qkv,
                                           (const float4*)w_proj, (uint4*)xb);

        gemm_qkv<<<dim3(36, 16), 256, 0, stream>>>(xb, wqkvb, qk, vt);
        norm_rope_k<<<12288, 256, 0, stream>>>(qk, pe, k_scale);
        attn2<<<dim3(24, 16), 256, 0, stream>>>(qk, vt, pe, q_scale);
        gemm_proj<<<dim3(24, 16), 256, 0, stream>>>(qk, wprojb, b_proj, out);
        return;
    }

    if (ws_size < 37748736ull) {             // ---- can't run at all ----
        fill_two<<<(6291456 + 255) / 256, 256, 0, stream>>>(out, 6291456);
        return;
    }

    // ---- slow path (round 4, proven) ----
    unsigned short* qk = (unsigned short*)d_ws;
    unsigned short* vt = qk + 12582912;

    gemm_bt<true, true, false, false, false><<<dim3(16, 48), 256, 0, stream>>>(
        x, w_qkv, nullptr, qk, 2048, 6144, 3072, 3072, 6144);
    norm_rope<<<24576, 256, 0, stream>>>(qk, pe, q_scale, k_scale);
    gemm_bt<true, true, false, false, true><<<dim3(16, 24), 256, 0, stream>>>(
        x, w_qkv + (size_t)6144 * 3072, nullptr, vt, 2048, 3072, 3072, 3072, 2048);
    attn_slow<<<dim3(16, 24), 256, 0, stream>>>(qk, vt);
    gemm_bt<false, true, true, true, false><<<dim3(16, 24), 256, 0, stream>>>(
        qk, w_proj, b_proj, out, 2048, 3072, 3072, 6144, 3072);
}

// Round 11
// 547.066 us; speedup vs baseline: 1.5446x; 1.0349x over previous
//
#include <hip/hip_runtime.h>

typedef __attribute__((ext_vector_type(8))) __bf16 bf16x8;
typedef __attribute__((ext_vector_type(4))) float f32x4;

typedef __attribute__((address_space(1))) void gvoid;
typedef __attribute__((address_space(3))) void lvoid;

__device__ __forceinline__ float bf2f(unsigned int u) {
    union { unsigned int u; float f; } v; v.u = u << 16; return v.f;
}
__device__ __forceinline__ unsigned short f2bf(float f) {
    union { float f; unsigned int u; } v; v.f = f;
    unsigned int r = v.u + 0x7fffu + ((v.u >> 16) & 1u);
    return (unsigned short)(r >> 16);
}
__device__ __forceinline__ unsigned int pack2(float a, float b) {
    return (unsigned int)f2bf(a) | ((unsigned int)f2bf(b) << 16);
}
__device__ __forceinline__ void async16(const void* g, void* l) {
    __builtin_amdgcn_global_load_lds((gvoid*)g, (lvoid*)l, 16, 0, 0);
}
// 2^x via v_exp_f32 (native). __exp2f is NOT declared in this env's headers.
__device__ __forceinline__ float exp2f_hw(float x) {
    return __builtin_amdgcn_exp2f(x);
}

// sum of squares of 8 bf16 (fp32 accumulation)
__device__ __forceinline__ float ssq8(bf16x8 v) {
    const unsigned int* u = (const unsigned int*)&v;
    float s = 0.0f;
#pragma unroll
    for (int j = 0; j < 4; ++j) {
        float x0 = bf2f(u[j] & 0xffffu), x1 = bf2f(u[j] >> 16);
        s += x0 * x0 + x1 * x1;
    }
    return s;
}
// RMSNorm(+scale)+RoPE applied to 8 bf16 (4 rope pairs, cols even-aligned).
// sc -> scale[gc..gc+7]; per -> &pe[(l*64 + gc/2)*4] (4 consecutive float4).
__device__ __forceinline__ bf16x8 normrope8(bf16x8 v, float rr,
                                            const float* __restrict__ sc,
                                            const float* __restrict__ per) {
    const unsigned int* u = (const unsigned int*)&v;
    bf16x8 out;
    unsigned int* ou = (unsigned int*)&out;
#pragma unroll
    for (int j = 0; j < 4; ++j) {
        float x0 = bf2f(u[j] & 0xffffu), x1 = bf2f(u[j] >> 16);
        float y0 = x0 * rr * sc[2 * j], y1 = x1 * rr * sc[2 * j + 1];
        float4 p4 = *(const float4*)(per + 4 * j);
        ou[j] = pack2(p4.x * y0 + p4.y * y1, p4.z * y0 + p4.w * y1);
    }
    return out;
}

// ============================ FAST PATH ====================================

// Fused fp32->bf16 convert of all three tensors in ONE launch (dst regions
// are contiguous in ws: xb @0 | wqkvb @786432 | wprojb @4325376, uint4 units).
__global__ __launch_bounds__(256)
void cvt_all(const float4* __restrict__ x, const float4* __restrict__ wqkv,
             const float4* __restrict__ wproj, uint4* __restrict__ dst) {
    int i = blockIdx.x * 256 + threadIdx.x;
    const float4* s; uint4* d; int off;
    if (i < 786432)       { s = x;     d = dst;           off = i; }
    else if (i < 4325376) { s = wqkv;  d = dst + 786432;  off = i - 786432; }
    else if (i < 5505024) { s = wproj; d = dst + 4325376; off = i - 4325376; }
    else return;
    float4 a = s[2 * off], b = s[2 * off + 1];
    uint4 o;
    o.x = pack2(a.x, a.y); o.y = pack2(a.z, a.w);
    o.z = pack2(b.x, b.y); o.w = pack2(b.z, b.w);
    d[off] = o;
}

// ---- 128x128 ring core — retained for gemm_proj (round-3 proven) ----
#define GEMM_CORE(A_, lda_, B_, ldb_, K_)                                        \
    __shared__ __align__(16) unsigned short As[4][4096];                         \
    __shared__ __align__(16) unsigned short Bs[4][4096];                         \
    const int t = threadIdx.x, lane = t & 63;                                    \
    const int wm = t >> 7, wn = (t >> 6) & 1;                                    \
    const int lr = lane & 15, kc = lane >> 4;                                    \
    const int NK = (K_) / 32;                                                    \
    const int e0 = t * 8, e1 = (256 + t) * 8;                                    \
    const int r0 = e0 >> 5, c0 = (e0 >> 3) & 3;                                  \
    const int r1 = e1 >> 5, c1 = (e1 >> 3) & 3;                                  \
    const int g0 = (c0 ^ ((r0 >> 1) & 3)) * 8;                                   \
    const int g1 = (c1 ^ ((r1 >> 1) & 3)) * 8;                                   \
    const unsigned short* Ag0 = &(A_)[(size_t)(m0 + r0) * (lda_) + g0];          \
    const unsigned short* Ag1 = &(A_)[(size_t)(m0 + r1) * (lda_) + g1];          \
    const unsigned short* Bg0 = &(B_)[(size_t)(n0 + r0) * (ldb_) + g0];          \
    const unsigned short* Bg1 = &(B_)[(size_t)(n0 + r1) * (ldb_) + g1];          \
    f32x4 acc[4][4] = {};                                                        \
    RSTAGE(0) RSTAGE(1) RSTAGE(2)                                                \
    asm volatile("s_waitcnt vmcnt(8)" ::: "memory");                             \
    __builtin_amdgcn_s_barrier();                                                \
    for (int kt = 0; kt < NK; ++kt) {                                            \
        const int sl = kt & 3;                                                   \
        bf16x8 af[4], bfr[4];                                                    \
        _Pragma("unroll")                                                        \
        for (int i = 0; i < 4; ++i) {                                            \
            int ra = wm * 64 + i * 16 + lr;                                      \
            int rb = wn * 64 + i * 16 + lr;                                      \
            af[i]  = *(const bf16x8*)&As[sl][ra * 32 + ((kc ^ ((ra >> 1) & 3)) * 8)]; \
            bfr[i] = *(const bf16x8*)&Bs[sl][rb * 32 + ((kc ^ ((rb >> 1) & 3)) * 8)]; \
        }                                                                        \
        if (kt + 3 < NK) RSTAGE(kt + 3)                                          \
        asm volatile("s_waitcnt lgkmcnt(0)" ::: "memory");                       \
        __builtin_amdgcn_sched_barrier(0);                                       \
        __builtin_amdgcn_s_setprio(1);                                           \
        _Pragma("unroll")                                                        \
        for (int mi = 0; mi < 4; ++mi)                                           \
            _Pragma("unroll")                                                    \
            for (int ni = 0; ni < 4; ++ni)                                       \
                acc[mi][ni] = __builtin_amdgcn_mfma_f32_16x16x32_bf16(           \
                    af[mi], bfr[ni], acc[mi][ni], 0, 0, 0);                      \
        __builtin_amdgcn_s_setprio(0);                                           \
        if (kt + 3 < NK)      { asm volatile("s_waitcnt vmcnt(8)" ::: "memory"); } \
        else if (kt + 2 < NK) { asm volatile("s_waitcnt vmcnt(4)" ::: "memory"); } \
        else if (kt + 1 < NK) { asm volatile("s_waitcnt vmcnt(0)" ::: "memory"); } \
        __builtin_amdgcn_s_barrier();                                            \
    }

#define RSTAGE(kt_) { const int s_ = (kt_) & 3; const size_t k_ = (size_t)(kt_) * 32; \
        async16(Ag0 + k_, &As[s_][e0]); async16(Ag1 + k_, &As[s_][e1]);               \
        async16(Bg0 + k_, &Bs[s_][e0]); async16(Bg1 + k_, &Bs[s_][e1]); }

// Fused QKV GEMM — EXACT round-4 config (fastest measured: ~180 µs).
// 128x256 tile, 4 waves x [128m x 64n], BK=32, 3-slot LDS ring (72 KiB,
// 2 blocks/CU), depth-2 prefetch, counted vmcnt(6). No XCD remap.
// A=xb[2048][3072], B=wqkvb[9216][3072].
// cols <6144 -> qk[row][col]; cols >=6144 -> vt[col-6144][row] (V transposed).
__global__ __launch_bounds__(256, 2)
void gemm_qkv(const unsigned short* __restrict__ A, const unsigned short* __restrict__ B,
              unsigned short* __restrict__ qk, unsigned short* __restrict__ vt) {
    __shared__ __align__(16) unsigned short As[3][4096];   // 128 x 32
    __shared__ __align__(16) unsigned short Bs[3][8192];   // 256 x 32
    const int n0 = blockIdx.x * 256, m0 = blockIdx.y * 128;
    const int t = threadIdx.x, lane = t & 63, w = t >> 6;
    const int lr = lane & 15, kc = lane >> 4;
    const int NK = 96;                        // 3072 / 32

    const int ea0 = t * 8,         ra0 = ea0 >> 5, ca0 = (ea0 >> 3) & 3;
    const int ea1 = (256 + t) * 8, ra1 = ea1 >> 5, ca1 = (ea1 >> 3) & 3;
    const int ga0 = (ca0 ^ ((ra0 >> 1) & 3)) * 8;
    const int ga1 = (ca1 ^ ((ra1 >> 1) & 3)) * 8;
    const unsigned short* Ag0 = &A[(size_t)(m0 + ra0) * 3072 + ga0];
    const unsigned short* Ag1 = &A[(size_t)(m0 + ra1) * 3072 + ga1];
    int eb[4];
    const unsigned short* Bg[4];
#pragma unroll
    for (int i = 0; i < 4; ++i) {
        eb[i] = (i * 256 + t) * 8;
        int rb = eb[i] >> 5, cb = (eb[i] >> 3) & 3;
        int gb = (cb ^ ((rb >> 1) & 3)) * 8;
        Bg[i] = &B[(size_t)(n0 + rb) * 3072 + gb];
    }

#define QSTAGE(kt_) { const int s_ = (kt_) % 3; const size_t k_ = (size_t)(kt_) * 32; \
        async16(Ag0 + k_, &As[s_][ea0]); async16(Ag1 + k_, &As[s_][ea1]);             \
        async16(Bg[0] + k_, &Bs[s_][eb[0]]); async16(Bg[1] + k_, &Bs[s_][eb[1]]);     \
        async16(Bg[2] + k_, &Bs[s_][eb[2]]); async16(Bg[3] + k_, &Bs[s_][eb[3]]); }

    f32x4 acc[8][4] = {};

    QSTAGE(0) QSTAGE(1)
    asm volatile("s_waitcnt vmcnt(6)" ::: "memory");
    __builtin_amdgcn_s_barrier();

    for (int kt = 0; kt < NK; ++kt) {
        const int sl = kt % 3;
        bf16x8 af[8], bfr[4];
#pragma unroll
        for (int i = 0; i < 8; ++i) {
            int ra = i * 16 + lr;
            af[i] = *(const bf16x8*)&As[sl][ra * 32 + ((kc ^ ((ra >> 1) & 3)) * 8)];
        }
#pragma unroll
        for (int i = 0; i < 4; ++i) {
            int rb = w * 64 + i * 16 + lr;
            bfr[i] = *(const bf16x8*)&Bs[sl][rb * 32 + ((kc ^ ((rb >> 1) & 3)) * 8)];
        }
        if (kt + 2 < NK) QSTAGE(kt + 2)
        asm volatile("s_waitcnt lgkmcnt(0)" ::: "memory");
        __builtin_amdgcn_sched_barrier(0);
        __builtin_amdgcn_s_setprio(1);
#pragma unroll
        for (int mi = 0; mi < 8; ++mi)
#pragma unroll
            for (int ni = 0; ni < 4; ++ni)
                acc[mi][ni] = __builtin_amdgcn_mfma_f32_16x16x32_bf16(
                    af[mi], bfr[ni], acc[mi][ni], 0, 0, 0);
        __builtin_amdgcn_s_setprio(0);
        if (kt + 2 < NK) { asm volatile("s_waitcnt vmcnt(6)" ::: "memory"); }
        else             { asm volatile("s_waitcnt vmcnt(0)" ::: "memory"); }
        __builtin_amdgcn_s_barrier();
    }
#undef QSTAGE

    const int rb0 = kc * 4;
#pragma unroll
    for (int mi = 0; mi < 8; ++mi)
#pragma unroll
        for (int ni = 0; ni < 4; ++ni) {
            int col = n0 + w * 64 + ni * 16 + lr;
#pragma unroll
            for (int r = 0; r < 4; ++r) {
                int row = m0 + mi * 16 + rb0 + r;
                unsigned short v = f2bf(acc[mi][ni][r]);
                if (col < 6144) qk[(size_t)row * 6144 + col] = v;
                else            vt[(size_t)(col - 6144) * 2048 + row] = v;
            }
        }
}

// Proj GEMM: A=qk(attn out, lda 6144), B=wprojb[3072][3072], fp32 out + bias.
__global__ __launch_bounds__(256, 2)
void gemm_proj(const unsigned short* __restrict__ A, const unsigned short* __restrict__ B,
               const float* __restrict__ bias, float* __restrict__ out) {
    const int n0 = blockIdx.x * 128, m0 = blockIdx.y * 128;
    GEMM_CORE(A, 6144, B, 3072, 3072)
    const int rb0 = kc * 4;
#pragma unroll
    for (int mi = 0; mi < 4; ++mi)
#pragma unroll
        for (int ni = 0; ni < 4; ++ni) {
            int col = n0 + wn * 64 + ni * 16 + lr;
            float badd = bias[col];
#pragma unroll
            for (int r = 0; r < 4; ++r) {
                int row = m0 + wm * 64 + mi * 16 + rb0 + r;
                out[(size_t)row * 3072 + col] = acc[mi][ni][r] + badd;
            }
        }
}

// K-only RMSNorm+RoPE on qk cols 3072.. (Q is fused into attn2; K kept as a
// standalone pass — round-9 post-mortem: fusing K's transform into attn2's
// prefetch path exploded live ranges -> scratch spill. Q-only fusion safe.)
__global__ __launch_bounds__(256)
void norm_rope_k(unsigned short* __restrict__ qk, const float* __restrict__ pe,
                 const float* __restrict__ k_scale) {
    const int wid = threadIdx.x >> 6, lane = threadIdx.x & 63;
    int pid = blockIdx.x * 4 + wid;            // 0..49151
    const int h = pid >> 11, l = pid & 2047;

    unsigned short* src = qk + (size_t)l * 6144 + 3072 + h * 128 + lane * 2;
    unsigned int xu = *(const unsigned int*)src;
    float x0 = bf2f(xu & 0xffffu), x1 = bf2f(xu >> 16);
    float ss = x0 * x0 + x1 * x1;
#pragma unroll
    for (int off = 32; off >= 1; off >>= 1) ss += __shfl_xor(ss, off);
    float rr = rsqrtf(ss * (1.0f / 128.0f) + 1e-6f);

    float2 s2 = *(const float2*)(k_scale + lane * 2);
    float y0 = x0 * rr * s2.x;
    float y1 = x1 * rr * s2.y;

    float4 p4 = *(const float4*)(pe + ((size_t)l * 64 + lane) * 4);
    float o0 = p4.x * y0 + p4.y * y1;
    float o1 = p4.z * y0 + p4.w * y1;

    *(unsigned int*)src = pack2(o0, o1);
}

// Flash attention v7: block = 1 head x 64 q rows (4 waves x 16 rows).
// ROUND-11 CHANGE: back to the 64q/block grid (24,32)=768 blocks = EXACTLY
// 3 blocks/CU. The 128q grid (384 blocks) left 128 CUs with 2 resident
// blocks and 128 with 1 — equal-length blocks, no repacking -> wall = 2T
// vs 1.5T ideal (33% structural waste) and only 4-8 waves/CU. 768 blocks
// balance every CU at 12 waves/CU. Keeps ALL round-8/10 wins: fully
// deferred reductions (ballot trigger + per-lane lpart), T13 defer-max,
// T14 register prefetch, async16 swizzled staging, Q-normrope fusion.
// LDS 40KB (Ps 8KB). K arrives pre-transformed via norm_rope_k.
__global__ __launch_bounds__(256, 2)
void attn2(unsigned short* __restrict__ qk, const unsigned short* __restrict__ vt,
           const float* __restrict__ pe, const float* __restrict__ q_scale) {
    __shared__ __align__(16) unsigned short Ks[64 * 128];
    __shared__ __align__(16) unsigned short Vs[128 * 64];
    __shared__ __align__(16) unsigned short Ps[4 * 16 * 64];
    const int t = threadIdx.x, lane = t & 63, w = t >> 6;
    const int h = blockIdx.x, qblk = blockIdx.y * 64;
    const int lr = lane & 15, kc = lane >> 4;
    const float sc2 = 0.08838834764831845f * 1.4426950408889634f; // scale*log2e
    const float THR = 62.7f;                                      // 8 / sc2

    // ---- load Q fragments and apply RMSNorm+RoPE (once per block) ----
    bf16x8 aq[4];
    const int lq = qblk + w * 16 + lr;
#pragma unroll
    for (int ks = 0; ks < 4; ++ks)
        aq[ks] = *(const bf16x8*)&qk[(size_t)lq * 6144 + h * 128 + ks * 32 + kc * 8];
    {
        float ss = 0.0f;
#pragma unroll
        for (int ks = 0; ks < 4; ++ks) ss += ssq8(aq[ks]);
        ss += __shfl_xor(ss, 16); ss += __shfl_xor(ss, 32);   // 4 kc-groups = 128 elems
        float rr = rsqrtf(ss * (1.0f / 128.0f) + 1e-6f);
#pragma unroll
        for (int ks = 0; ks < 4; ++ks) {
            int c0 = ks * 32 + kc * 8;
            aq[ks] = normrope8(aq[ks], rr, q_scale + c0,
                               pe + ((size_t)lq * 64 + (c0 >> 1)) * 4);
        }
    }

    f32x4 o[8] = {};
    float mst[4], lpart[4];
#pragma unroll
    for (int r = 0; r < 4; ++r) { mst[r] = -1e30f; lpart[r] = 0.0f; }

    unsigned short* Pw = &Ps[w * 1024];

    // prologue: stage tile kb=0 via async16 (drained by first __syncthreads)
#pragma unroll
    for (int i = 0; i < 4; ++i) {
        int e = (i * 256 + t) * 8;
        {   // K tile [64 keys][128 d]
            int row = e >> 7, c8 = (e >> 3) & 15;
            int gc = (c8 ^ (row & 15)) * 8;
            async16(&qk[(size_t)row * 6144 + 3072 + h * 128 + gc], &Ks[e]);
        }
        {   // V^T tile [128 d][64 keys]
            int row = e >> 6, c8 = (e >> 3) & 7;
            int gc = (c8 ^ (row & 7)) * 8;
            async16(&vt[(size_t)(h * 128 + row) * 2048 + gc], &Vs[e]);
        }
    }

    for (int kb = 0; kb < 2048; kb += 64) {
        __syncthreads();                 // tile kb present in Ks/Vs

        // T14: issue register prefetch of tile kb+64 (hidden under compute)
        bf16x8 pk[4], pv[4];
        const bool pf = (kb + 64) < 2048;
        if (pf) {
#pragma unroll
            for (int i = 0; i < 4; ++i) {
                int e = (i * 256 + t) * 8;
                {   int row = e >> 7, c8 = (e >> 3) & 15;
                    int gc = (c8 ^ (row & 15)) * 8;
                    pk[i] = *(const bf16x8*)&qk[(size_t)(kb + 64 + row) * 6144 + 3072 + h * 128 + gc];
                }
                {   int row = e >> 6, c8 = (e >> 3) & 7;
                    int gc = (c8 ^ (row & 7)) * 8;
                    pv[i] = *(const bf16x8*)&vt[(size_t)(h * 128 + row) * 2048 + kb + 64 + gc];
                }
            }
        }

        // S = Q K^T  (C rows = q = kc*4+r, cols = key = nt*16+lr)
        f32x4 s[4] = {};
#pragma unroll
        for (int nt = 0; nt < 4; ++nt) {
            int rk = nt * 16 + lr;
#pragma unroll
            for (int ks = 0; ks < 4; ++ks) {
                int ck = ks * 4 + kc;
                bf16x8 bk = *(const bf16x8*)&Ks[rk * 128 + ((ck ^ (rk & 15)) * 8)];
                s[nt] = __builtin_amdgcn_mfma_f32_16x16x32_bf16(aq[ks], bk, s[nt], 0, 0, 0);
            }
        }

        // softmax, exp2 domain, fully deferred reductions
        {
            float lm[4]; bool need = false;
#pragma unroll
            for (int r = 0; r < 4; ++r) {
                lm[r] = fmaxf(fmaxf(s[0][r], s[1][r]), fmaxf(s[2][r], s[3][r]));
                need = need || (lm[r] > mst[r] + THR);
            }
            if (__ballot(need) != 0ull) {      // rare; always on first tile
#pragma unroll
                for (int r = 0; r < 4; ++r) {
                    float vmax = lm[r];
#pragma unroll
                    for (int off = 8; off >= 1; off >>= 1) vmax = fmaxf(vmax, __shfl_xor(vmax, off));
                    float mn = fmaxf(mst[r], vmax);
                    float al = exp2f_hw((mst[r] - mn) * sc2);
                    mst[r] = mn;
                    lpart[r] *= al;
#pragma unroll
                    for (int dt = 0; dt < 8; ++dt) o[dt][r] *= al;
                }
            }
#pragma unroll
            for (int r = 0; r < 4; ++r) {
                float ps = 0.0f;
#pragma unroll
                for (int nt = 0; nt < 4; ++nt) {
                    float p = exp2f_hw((s[nt][r] - mst[r]) * sc2);
                    s[nt][r] = p;
                    ps += p;
                }
                lpart[r] += ps;                // per-lane partial; no shuffles
            }
        }

        // P (C-layout) -> per-wave LDS [16 q][64 kk], chunk ^= (q&7)
#pragma unroll
        for (int nt = 0; nt < 4; ++nt) {
            int col = nt * 16 + lr;
            int chunk = col >> 3, cin = col & 7;
#pragma unroll
            for (int r = 0; r < 4; ++r) {
                int q = kc * 4 + r;
                Pw[q * 64 + ((chunk ^ (q & 7)) * 8 + cin)] = f2bf(s[nt][r]);
            }
        }

        // O += P @ V  (A = P[q][kk], B = Vt[d][kk])
#pragma unroll
        for (int ks2 = 0; ks2 < 2; ++ks2) {
            int ck = ks2 * 4 + kc;
            bf16x8 ap = *(const bf16x8*)&Pw[lr * 64 + ((ck ^ (lr & 7)) * 8)];
#pragma unroll
            for (int dt = 0; dt < 8; ++dt) {
                int rv = dt * 16 + lr;
                bf16x8 bv = *(const bf16x8*)&Vs[rv * 64 + ((ck ^ (rv & 7)) * 8)];
                o[dt] = __builtin_amdgcn_mfma_f32_16x16x32_bf16(ap, bv, o[dt], 0, 0, 0);
            }
        }
        __syncthreads();                 // all reads of tile kb done

        if (pf) {
#pragma unroll
            for (int i = 0; i < 4; ++i) {
                int e = (i * 256 + t) * 8;
                *(bf16x8*)&Ks[e] = pk[i];
                *(bf16x8*)&Vs[e] = pv[i];
            }
        }
    }

    // final cross-lane reduction of lpart (once), then write
#pragma unroll
    for (int r = 0; r < 4; ++r) {
        float ps = lpart[r];
#pragma unroll
        for (int off = 8; off >= 1; off >>= 1) ps += __shfl_xor(ps, off);
        lpart[r] = ps;
    }
#pragma unroll
    for (int dt = 0; dt < 8; ++dt)
#pragma unroll
        for (int r = 0; r < 4; ++r) {
            int row = qblk + w * 16 + kc * 4 + r;
            qk[(size_t)row * 6144 + h * 128 + dt * 16 + lr] = f2bf(o[dt][r] / lpart[r]);
        }
}

// ===================== SHARED (slow path only now) =========================

// In-place RMSNorm + RoPE on qk[2048][6144] bf16 (q cols 0..3071, k 3072+).
__global__ __launch_bounds__(256)
void norm_rope(unsigned short* __restrict__ qk, const float* __restrict__ pe,
               const float* __restrict__ q_scale, const float* __restrict__ k_scale) {
    const int wid = threadIdx.x >> 6, lane = threadIdx.x & 63;
    int pid = blockIdx.x * 4 + wid;
    const int isK = pid >= 49152;
    int p2 = isK ? pid - 49152 : pid;
    const int h = p2 >> 11, l = p2 & 2047;

    unsigned short* src = qk + (size_t)l * 6144 + (isK ? 3072 : 0) + h * 128 + lane * 2;
    unsigned int xu = *(const unsigned int*)src;
    float x0 = bf2f(xu & 0xffffu), x1 = bf2f(xu >> 16);
    float ss = x0 * x0 + x1 * x1;
#pragma unroll
    for (int off = 32; off >= 1; off >>= 1) ss += __shfl_xor(ss, off);
    float rr = rsqrtf(ss * (1.0f / 128.0f) + 1e-6f);

    const float* sc = isK ? k_scale : q_scale;
    float2 s2 = *(const float2*)(sc + lane * 2);
    float y0 = x0 * rr * s2.x;
    float y1 = x1 * rr * s2.y;

    float4 p4 = *(const float4*)(pe + ((size_t)l * 64 + lane) * 4);
    float o0 = p4.x * y0 + p4.y * y1;
    float o1 = p4.z * y0 + p4.w * y1;

    *(unsigned int*)src = pack2(o0, o1);
}

// ===================== SLOW PATH (round-4, proven) =========================

template <bool A32, bool B32, bool C32, bool HAS_BIAS, bool TRANS_C>
__global__ __launch_bounds__(256, 2)
void gemm_bt(const void* __restrict__ Ap, const void* __restrict__ Bp,
             const float* __restrict__ bias, void* __restrict__ Cp,
             int M, int N, int K, int lda, int ldc) {
    __shared__ __align__(16) unsigned short As[128 * 40];
    __shared__ __align__(16) unsigned short Bs[128 * 40];
    const int t = threadIdx.x, lane = t & 63;
    const int wm = t >> 7, wn = (t >> 6) & 1;
    const int m0 = blockIdx.x * 128, n0 = blockIdx.y * 128;
    const int lr = lane & 15, kc = lane >> 4;
    f32x4 acc[4][4] = {};

    for (int k0 = 0; k0 < K; k0 += 32) {
        float4 ra32[4], rb32[4];
        bf16x8 ra16[2], rb16[2];
        if constexpr (A32) {
            const float* A = (const float*)Ap;
#pragma unroll
            for (int i = 0; i < 4; ++i) {
                int idx = i * 256 + t, row = idx >> 3, c4 = idx & 7;
                ra32[i] = *(const float4*)&A[(size_t)(m0 + row) * lda + k0 + c4 * 4];
            }
        } else {
            const unsigned short* A = (const unsigned short*)Ap;
#pragma unroll
            for (int i = 0; i < 2; ++i) {
                int idx = i * 256 + t, row = idx >> 2, c8 = idx & 3;
                ra16[i] = *(const bf16x8*)&A[(size_t)(m0 + row) * lda + k0 + c8 * 8];
            }
        }
        if constexpr (B32) {
            const float* B = (const float*)Bp;
#pragma unroll
            for (int i = 0; i < 4; ++i) {
                int idx = i * 256 + t, row = idx >> 3, c4 = idx & 7;
                rb32[i] = *(const float4*)&B[(size_t)(n0 + row) * K + k0 + c4 * 4];
            }
        } else {
            const unsigned short* B = (const unsigned short*)Bp;
#pragma unroll
            for (int i = 0; i < 2; ++i) {
                int idx = i * 256 + t, row = idx >> 2, c8 = idx & 3;
                rb16[i] = *(const bf16x8*)&B[(size_t)(n0 + row) * K + k0 + c8 * 8];
            }
        }
        __syncthreads();
        if constexpr (A32) {
#pragma unroll
            for (int i = 0; i < 4; ++i) {
                int idx = i * 256 + t, row = idx >> 3, c4 = idx & 7;
                uint2 p = { pack2(ra32[i].x, ra32[i].y), pack2(ra32[i].z, ra32[i].w) };
                *(uint2*)&As[row * 40 + c4 * 4] = p;
            }
        } else {
#pragma unroll
            for (int i = 0; i < 2; ++i) {
                int idx = i * 256 + t, row = idx >> 2, c8 = idx & 3;
                *(bf16x8*)&As[row * 40 + c8 * 8] = ra16[i];
            }
        }
        if constexpr (B32) {
#pragma unroll
            for (int i = 0; i < 4; ++i) {
                int idx = i * 256 + t, row = idx >> 3, c4 = idx & 7;
                uint2 p = { pack2(rb32[i].x, rb32[i].y), pack2(rb32[i].z, rb32[i].w) };
                *(uint2*)&Bs[row * 40 + c4 * 4] = p;
            }
        } else {
#pragma unroll
            for (int i = 0; i < 2; ++i) {
                int idx = i * 256 + t, row = idx >> 2, c8 = idx & 3;
                *(bf16x8*)&Bs[row * 40 + c8 * 8] = rb16[i];
            }
        }
        __syncthreads();
        bf16x8 af[4], bfr[4];
#pragma unroll
        for (int i = 0; i < 4; ++i) {
            af[i]  = *(const bf16x8*)&As[(wm * 64 + i * 16 + lr) * 40 + kc * 8];
            bfr[i] = *(const bf16x8*)&Bs[(wn * 64 + i * 16 + lr) * 40 + kc * 8];
        }
#pragma unroll
        for (int mi = 0; mi < 4; ++mi)
#pragma unroll
            for (int ni = 0; ni < 4; ++ni)
                acc[mi][ni] = __builtin_amdgcn_mfma_f32_16x16x32_bf16(af[mi], bfr[ni], acc[mi][ni], 0, 0, 0);
    }
    const int rb0 = kc * 4;
#pragma unroll
    for (int mi = 0; mi < 4; ++mi) {
#pragma unroll
        for (int ni = 0; ni < 4; ++ni) {
            int col = n0 + wn * 64 + ni * 16 + lr;
            float badd = HAS_BIAS ? bias[col] : 0.0f;
#pragma unroll
            for (int r = 0; r < 4; ++r) {
                int row = m0 + wm * 64 + mi * 16 + rb0 + r;
                size_t off = TRANS_C ? ((size_t)col * ldc + row) : ((size_t)row * ldc + col);
                if (C32) ((float*)Cp)[off] = acc[mi][ni][r] + badd;
                else     ((unsigned short*)Cp)[off] = f2bf(acc[mi][ni][r] + badd);
            }
        }
    }
}

__global__ __launch_bounds__(256, 2)
void attn_slow(unsigned short* __restrict__ qk, const unsigned short* __restrict__ vt) {
    __shared__ __align__(16) unsigned short Ks[64 * 136];
    __shared__ __align__(16) unsigned short Vs[128 * 72];
    __shared__ __align__(16) unsigned short Ps[4 * 32 * 72];
    const int t = threadIdx.x, lane = t & 63, w = t >> 6;
    const int h = blockIdx.y, q0 = blockIdx.x * 128;
    const int lr = lane & 15, kc = lane >> 4;
    const float scale = 0.08838834764831845f;

    bf16x8 aq[2][4];
#pragma unroll
    for (int mf = 0; mf < 2; ++mf)
#pragma unroll
        for (int ks = 0; ks < 4; ++ks)
            aq[mf][ks] = *(const bf16x8*)&qk[(size_t)(q0 + w * 32 + mf * 16 + lr) * 6144 + h * 128 + ks * 32 + kc * 8];

    f32x4 o[2][8] = {};
    float mst[2][4], lst[2][4];
#pragma unroll
    for (int mf = 0; mf < 2; ++mf)
#pragma unroll
        for (int r = 0; r < 4; ++r) { mst[mf][r] = -1e30f; lst[mf][r] = 0.0f; }

    unsigned short* Pw = &Ps[w * 32 * 72];

    for (int kb = 0; kb < 2048; kb += 64) {
        bf16x8 rk[4], rv[4];
#pragma unroll
        for (int i = 0; i < 4; ++i) {
            int idx = i * 256 + t;
            { int row = idx >> 4, c8 = idx & 15;
              rk[i] = *(const bf16x8*)&qk[(size_t)(kb + row) * 6144 + 3072 + h * 128 + c8 * 8]; }
            { int row = idx >> 3, c8 = idx & 7;
              rv[i] = *(const bf16x8*)&vt[(size_t)(h * 128 + row) * 2048 + kb + c8 * 8]; }
        }
        __syncthreads();
#pragma unroll
        for (int i = 0; i < 4; ++i) {
            int idx = i * 256 + t;
            { int row = idx >> 4, c8 = idx & 15; *(bf16x8*)&Ks[row * 136 + c8 * 8] = rk[i]; }
            { int row = idx >> 3, c8 = idx & 7;  *(bf16x8*)&Vs[row * 72 + c8 * 8] = rv[i]; }
        }
        __syncthreads();

        f32x4 s[2][4] = {};
#pragma unroll
        for (int nt = 0; nt < 4; ++nt) {
            int rkr = nt * 16 + lr;
#pragma unroll
            for (int ks = 0; ks < 4; ++ks) {
                bf16x8 bk = *(const bf16x8*)&Ks[rkr * 136 + (ks * 4 + kc) * 8];
#pragma unroll
                for (int mf = 0; mf < 2; ++mf)
                    s[mf][nt] = __builtin_amdgcn_mfma_f32_16x16x32_bf16(aq[mf][ks], bk, s[mf][nt], 0, 0, 0);
            }
        }
#pragma unroll
        for (int mf = 0; mf < 2; ++mf)
#pragma unroll
            for (int nt = 0; nt < 4; ++nt)
#pragma unroll
                for (int r = 0; r < 4; ++r) s[mf][nt][r] *= scale;

#pragma unroll
        for (int mf = 0; mf < 2; ++mf) {
#pragma unroll
            for (int r = 0; r < 4; ++r) {
                float vmax = fmaxf(fmaxf(s[mf][0][r], s[mf][1][r]), fmaxf(s[mf][2][r], s[mf][3][r]));
#pragma unroll
                for (int off = 8; off >= 1; off >>= 1) vmax = fmaxf(vmax, __shfl_xor(vmax, off));
                float mn = fmaxf(mst[mf][r], vmax);
                float al = __expf(mst[mf][r] - mn);
                mst[mf][r] = mn;
                float ps = 0.0f;
#pragma unroll
                for (int nt = 0; nt < 4; ++nt) {
                    float p = __expf(s[mf][nt][r] - mn);
                    s[mf][nt][r] = p;
                    ps += p;
                }
#pragma unroll
                for (int off = 8; off >= 1; off >>= 1) ps += __shfl_xor(ps, off);
                lst[mf][r] = lst[mf][r] * al + ps;
#pragma unroll
                for (int dt = 0; dt < 8; ++dt) o[mf][dt][r] *= al;
            }
        }

#pragma unroll
        for (int mf = 0; mf < 2; ++mf)
#pragma unroll
            for (int nt = 0; nt < 4; ++nt)
#pragma unroll
                for (int r = 0; r < 4; ++r)
                    Pw[(mf * 16 + kc * 4 + r) * 72 + nt * 16 + lr] = f2bf(s[mf][nt][r]);

#pragma unroll
        for (int ks2 = 0; ks2 < 2; ++ks2) {
            bf16x8 ap[2];
#pragma unroll
            for (int mf = 0; mf < 2; ++mf)
                ap[mf] = *(const bf16x8*)&Pw[(mf * 16 + lr) * 72 + (ks2 * 4 + kc) * 8];
#pragma unroll
            for (int dt = 0; dt < 8; ++dt) {
                bf16x8 bv = *(const bf16x8*)&Vs[(dt * 16 + lr) * 72 + (ks2 * 4 + kc) * 8];
#pragma unroll
                for (int mf = 0; mf < 2; ++mf)
                    o[mf][dt] = __builtin_amdgcn_mfma_f32_16x16x32_bf16(ap[mf], bv, o[mf][dt], 0, 0, 0);
            }
        }
        __syncthreads();
    }

#pragma unroll
    for (int mf = 0; mf < 2; ++mf)
#pragma unroll
        for (int dt = 0; dt < 8; ++dt)
#pragma unroll
            for (int r = 0; r < 4; ++r) {
                int row = q0 + w * 32 + mf * 16 + kc * 4 + r;
                qk[(size_t)row * 6144 + h * 128 + dt * 16 + lr] = f2bf(o[mf][dt][r] / lst[mf][r]);
            }
}

__global__ void fill_two(float* p, int n) {
    int i = blockIdx.x * 256 + threadIdx.x;
    if (i < n) p[i] = 2.0f;
}

// ---------------------------------------------------------------------------
// Fast path (ws >= 120 MiB), shorts offsets:
//   xb 0 | wqkvb 6291456 | wprojb 34603008 | qk 44040192 | vt 56623104
// Slow path: round-4 layout (qk @0, vt @12582912), peak 36 MiB.
// ---------------------------------------------------------------------------
extern "C" void kernel_launch(void* const* d_in, const int* in_sizes, int n_in,
                              void* d_out, int out_size, void* d_ws, size_t ws_size,
                              hipStream_t stream) {
    const float* x       = (const float*)d_in[0];
    const float* pe      = (const float*)d_in[1];
    const float* w_qkv   = (const float*)d_in[2];
    const float* q_scale = (const float*)d_in[3];
    const float* k_scale = (const float*)d_in[4];
    const float* w_proj  = (const float*)d_in[5];
    const float* b_proj  = (const float*)d_in[6];
    float* out = (float*)d_out;

    if (ws_size >= 125829120ull) {           // ---- fast path ----
        unsigned short* ws     = (unsigned short*)d_ws;
        unsigned short* xb     = ws;
        unsigned short* wqkvb  = ws + 6291456;
        unsigned short* wprojb = ws + 34603008;
        unsigned short* qk     = ws + 44040192;
        unsigned short* vt     = ws + 56623104;

        cvt_all<<<21504, 256, 0, stream>>>((const float4*)x, (const float4*)w_qkv,
                                           (const float4*)w_proj, (uint4*)xb);

        gemm_qkv<<<dim3(36, 16), 256, 0, stream>>>(xb, wqkvb, qk, vt);
        norm_rope_k<<<12288, 256, 0, stream>>>(qk, pe, k_scale);
        attn2<<<dim3(24, 32), 256, 0, stream>>>(qk, vt, pe, q_scale);
        gemm_proj<<<dim3(24, 16), 256, 0, stream>>>(qk, wprojb, b_proj, out);
        return;
    }

    if (ws_size < 37748736ull) {             // ---- can't run at all ----
        fill_two<<<(6291456 + 255) / 256, 256, 0, stream>>>(out, 6291456);
        return;
    }

    // ---- slow path (round 4, proven) ----
    unsigned short* qk = (unsigned short*)d_ws;
    unsigned short* vt = qk + 12582912;

    gemm_bt<true, true, false, false, false><<<dim3(16, 48), 256, 0, stream>>>(
        x, w_qkv, nullptr, qk, 2048, 6144, 3072, 3072, 6144);
    norm_rope<<<24576, 256, 0, stream>>>(qk, pe, q_scale, k_scale);
    gemm_bt<true, true, false, false, true><<<dim3(16, 24), 256, 0, stream>>>(
        x, w_qkv + (size_t)6144 * 3072, nullptr, vt, 2048, 3072, 3072, 3072, 2048);
    attn_slow<<<dim3(16, 24), 256, 0, stream>>>(qk, vt);
    gemm_bt<false, true, true, true, false><<<dim3(16, 24), 256, 0, stream>>>(
        qk, w_proj, b_proj, out, 2048, 3072, 3072, 6144, 3072);
}